// Round 3
// baseline (7027.498 us; speedup 1.0000x reference)
//
#include <hip/hip_runtime.h>
#include <math.h>

// VectorQuantizer: x (32768,64) f32, codebook (8192,64) f32, start/end/use_sk ints.
// Outputs concat: x_q_st (2097152 f32) | loss (1 f32) | indices (32768 as f32 values).
//
// R3 architecture: two-pass filter.
//  Pass 1 (vq_pass1): fp32-FMA tiled GEMM computing g_k = sc_k - 2*dot(x,c_k); records
//    min g per (token, 128-code chunk). FMA is fine here: |g_fma - g_numpy| < 1e-9 while
//    the reference's own d = fl(fl(sx+sc)-2t) carries <= 7.6e-6 rounding slop (ulp@64).
//    Any code that can be the reference argmin satisfies g <= min_g + 2*eps, eps ~= 8e-6.
//  Pass 2 (vq_select): rescan flagged chunks (window W=1e-4, 6x margin; expect ~1.15
//    chunks/token) with the BIT-EXACT numpy-replica arithmetic validated in R1
//    (pairwise-8, separate mul+add, strict-< first-occurrence, ascending k).
//  Then gather + loss exactly as R1 (validated, absmax 0.0).
// DO NOT change the exact-path arithmetic: inter-code d gaps are ~1 ulp of d.

#define N_E    8192
#define EDIM   64
#define NTOK   32768
#define NELEM  (NTOK * EDIM)       // 2097152
#define TM     64                  // pass-1 token tile
#define TN     128                 // pass-1 code tile == chunk size
#define NCHUNK (N_E / TN)          // 64 chunks
#define WINDOW 1e-4f

// ---------------- k1: codebook squared norms (np.sum pairwise-8 replica) -------------
__global__ __launch_bounds__(256) void vq_sc(const float* __restrict__ cb,
                                             float* __restrict__ sc) {
#pragma clang fp contract(off)
  int r = blockIdx.x * 256 + threadIdx.x;
  const float4* c4 = (const float4*)(cb + (size_t)r * EDIM);
  float a[8];
#pragma unroll
  for (int j = 0; j < 8; ++j) a[j] = 0.0f;
#pragma unroll
  for (int i = 0; i < 8; ++i) {
    float4 pA = c4[2*i], pB = c4[2*i+1];
    a[0] += pA.x * pA.x; a[1] += pA.y * pA.y; a[2] += pA.z * pA.z; a[3] += pA.w * pA.w;
    a[4] += pB.x * pB.x; a[5] += pB.y * pB.y; a[6] += pB.z * pB.z; a[7] += pB.w * pB.w;
  }
  sc[r] = ((a[0]+a[1]) + (a[2]+a[3])) + ((a[4]+a[5]) + (a[6]+a[7]));
}

// ---------------- pass 1: approximate GEMM + per-chunk minima ------------------------
// Block tile: 64 tokens x 128 codes, K=64 staged once in LDS (k-major, transposed).
// Thread micro-tile: 8 tokens x 4 codes (tx in [0,32) codes, ty in [0,8) tokens).
__global__ __launch_bounds__(256, 4) void vq_pass1(
    const float* __restrict__ x, const float* __restrict__ cb,
    const float* __restrict__ sc, float* __restrict__ minima,
    const int* __restrict__ p_start, const int* __restrict__ p_end) {
  __shared__ float Xs[64][68];    // [k][token]  17408 B (68: b128-aligned rows, depad)
  __shared__ float Cs[64][132];   // [k][code]   33792 B
  int tid = threadIdx.x;
  int tb = blockIdx.x;            // token tile [0, 512)
  int nb = blockIdx.y;            // code tile / chunk [0, 64)
  const float4* xg = (const float4*)(x  + (size_t)tb * TM * EDIM);
  const float4* cg = (const float4*)(cb + (size_t)nb * TN * EDIM);

  // Stage X tile: 64 rows x 16 float4 = 1024 float4, coalesced; transpose into Xs.
#pragma unroll
  for (int p = 0; p < 4; ++p) {
    int idx = tid + p * 256;
    int m = idx >> 4, j = idx & 15;
    float4 v = xg[idx];
    Xs[4*j+0][m] = v.x; Xs[4*j+1][m] = v.y; Xs[4*j+2][m] = v.z; Xs[4*j+3][m] = v.w;
  }
  // Stage C tile: 128 rows x 16 float4 = 2048 float4.
#pragma unroll
  for (int p = 0; p < 8; ++p) {
    int idx = tid + p * 256;
    int n = idx >> 4, j = idx & 15;
    float4 v = cg[idx];
    Cs[4*j+0][n] = v.x; Cs[4*j+1][n] = v.y; Cs[4*j+2][n] = v.z; Cs[4*j+3][n] = v.w;
  }
  __syncthreads();

  int tx = tid & 31, ty = tid >> 5;
  int m0 = ty * 8, n0 = tx * 4;
  float acc[8][4];
#pragma unroll
  for (int i = 0; i < 8; ++i)
#pragma unroll
    for (int j = 0; j < 4; ++j) acc[i][j] = 0.0f;

#pragma unroll 4
  for (int k = 0; k < 64; ++k) {
    float4 cv  = *(const float4*)&Cs[k][n0];
    float4 xv0 = *(const float4*)&Xs[k][m0];
    float4 xv1 = *(const float4*)&Xs[k][m0 + 4];
    float xs[8] = {xv0.x, xv0.y, xv0.z, xv0.w, xv1.x, xv1.y, xv1.z, xv1.w};
    float cs[4] = {cv.x, cv.y, cv.z, cv.w};
#pragma unroll
    for (int i = 0; i < 8; ++i)
#pragma unroll
      for (int j = 0; j < 4; ++j) acc[i][j] = fmaf(xs[i], cs[j], acc[i][j]);
  }

  __syncthreads();                 // all Xs reads done before reuse as reduction space
  float* sred = &Xs[0][0];         // 64 tokens x 32 lanes, stride 33 (2-way = free)
  int s = *p_start, e = *p_end;
  float4 sc4 = *(const float4*)&sc[nb * TN + n0];
  float scv[4] = {sc4.x, sc4.y, sc4.z, sc4.w};
#pragma unroll
  for (int i = 0; i < 8; ++i) {
    float v = INFINITY;
#pragma unroll
    for (int j = 0; j < 4; ++j) {
      int gk = nb * TN + n0 + j;
      float g = scv[j] - 2.0f * acc[i][j];
      if (gk >= s && gk < e) v = fminf(v, g);
    }
    sred[(m0 + i) * 33 + tx] = v;
  }
  __syncthreads();
  if (tid < 64) {
    float v = INFINITY;
#pragma unroll 8
    for (int t = 0; t < 32; ++t) v = fminf(v, sred[tid * 33 + t]);
    minima[(size_t)(tb * TM + tid) * NCHUNK + nb] = v;
  }
}

// ---------------- pass 2: exact rescan of flagged chunks -----------------------------
// thread = token. Bit-exact numpy-replica d (validated R1) on ~1.15 chunks/token.
__global__ __launch_bounds__(256) void vq_select(
    const float* __restrict__ x, const float* __restrict__ cb,
    const float* __restrict__ sc, const float* __restrict__ minima,
    float* __restrict__ bestidx,
    const int* __restrict__ p_start, const int* __restrict__ p_end) {
#pragma clang fp contract(off)
  int token = blockIdx.x * 256 + threadIdx.x;
  const float* row = minima + (size_t)token * NCHUNK;

  float m = INFINITY;
  for (int c = 0; c < NCHUNK; ++c) m = fminf(m, row[c]);
  float thresh = m + WINDOW;

  const float* xr = x + (size_t)token * EDIM;
  float xv[EDIM];
#pragma unroll
  for (int j = 0; j < EDIM / 4; ++j) {
    float4 f = ((const float4*)xr)[j];
    xv[4*j+0] = f.x; xv[4*j+1] = f.y; xv[4*j+2] = f.z; xv[4*j+3] = f.w;
  }
  // sx = np.sum(x*x) pairwise-8 replica
  float a[8];
#pragma unroll
  for (int j = 0; j < 8; ++j) a[j] = xv[j] * xv[j];
#pragma unroll
  for (int i = 8; i < EDIM; i += 8)
#pragma unroll
    for (int j = 0; j < 8; ++j) a[j] += xv[i+j] * xv[i+j];
  float sx = ((a[0]+a[1]) + (a[2]+a[3])) + ((a[4]+a[5]) + (a[6]+a[7]));

  int s = *p_start, e = *p_end;
  float bd = INFINITY;
  float bi = -1.0f;
  for (int c = 0; c < NCHUNK; ++c) {
    if (!(row[c] <= thresh)) continue;         // skips INF chunks too
    int kb = c * TN; if (kb < s) kb = s;
    int ke = c * TN + TN; if (ke > e) ke = e;
    for (int k = kb; k < ke; ++k) {
      const float4* c4 = (const float4*)(cb + (size_t)k * EDIM);
      float t[8];
#pragma unroll
      for (int j = 0; j < 8; ++j) t[j] = 0.0f;
#pragma unroll
      for (int h = 0; h < 2; ++h) {
        float cv[32];
#pragma unroll
        for (int j = 0; j < 8; ++j) {
          float4 f = c4[h*8 + j];
          cv[4*j+0] = f.x; cv[4*j+1] = f.y; cv[4*j+2] = f.z; cv[4*j+3] = f.w;
        }
#pragma unroll
        for (int i = 0; i < 4; ++i)
#pragma unroll
          for (int j = 0; j < 8; ++j)
            t[j] += cv[i*8 + j] * xv[h*32 + i*8 + j];
      }
      float tt = ((t[0]+t[1]) + (t[2]+t[3])) + ((t[4]+t[5]) + (t[6]+t[7]));
      float d = (sx + sc[k]) - 2.0f * tt;
      if (d < bd) { bd = d; bi = (float)k; }   // strict <, ascending k: first occurrence
    }
  }
  bestidx[token] = bi;
}

// ---------------- k3: gather, x_q_st, loss partials ----------------------------------
__global__ __launch_bounds__(256) void vq_combine(
    const float* __restrict__ x, const float* __restrict__ cb,
    const float* __restrict__ bestidx, float* __restrict__ out_xq,
    float* __restrict__ out_idx, float* __restrict__ partial) {
#pragma clang fp contract(off)
  int tid  = threadIdx.x;
  int wv   = tid >> 6;
  int lane = tid & 63;
  int token = blockIdx.x * 4 + wv;

  float bi = bestidx[token];
  int bidx = (int)bi;

  float q  = cb[(size_t)bidx * EDIM + lane];
  float xx = x[(size_t)token * EDIM + lane];
  float diff = q - xx;                              // fl(x_q - x)
  out_xq[(size_t)token * EDIM + lane] = xx + diff;  // fl(x + fl(x_q - x))
  if (lane == 0) out_idx[token] = bi;

  float l = diff * diff;
#pragma unroll
  for (int off = 32; off >= 1; off >>= 1) l += __shfl_down(l, off, 64);
  __shared__ float sdata[4];
  if (lane == 0) sdata[wv] = l;
  __syncthreads();
  if (tid == 0) partial[blockIdx.x] = (sdata[0] + sdata[1]) + (sdata[2] + sdata[3]);
}

// ---------------- k4: final loss reduction -------------------------------------------
__global__ __launch_bounds__(256) void vq_loss(const float* __restrict__ partial,
                                               float* __restrict__ out_loss) {
  int tid = threadIdx.x;
  float s = 0.0f;
  for (int i = tid; i < NTOK / 4; i += 256) s += partial[i];
#pragma unroll
  for (int off = 32; off >= 1; off >>= 1) s += __shfl_down(s, off, 64);
  __shared__ float sdata[4];
  if ((tid & 63) == 0) sdata[tid >> 6] = s;
  __syncthreads();
  if (tid == 0) {
    float total = (sdata[0] + sdata[1]) + (sdata[2] + sdata[3]);
    float m = total * (1.0f / (float)NELEM);
    out_loss[0] = m + 0.25f * m;
  }
}

// ---------------- launch -------------------------------------------------------------
extern "C" void kernel_launch(void* const* d_in, const int* in_sizes, int n_in,
                              void* d_out, int out_size, void* d_ws, size_t ws_size,
                              hipStream_t stream) {
  const float* x  = (const float*)d_in[0];
  const float* cb = (const float*)d_in[1];
  const int* p_start = (const int*)d_in[2];
  const int* p_end   = (const int*)d_in[3];

  float* ws = (float*)d_ws;
  float* sc      = ws;                                   // 8192
  float* minima  = ws + N_E;                             // 32768*64 = 2.09M floats
  float* bestidx = minima + (size_t)NTOK * NCHUNK;       // 32768
  float* partial = bestidx + NTOK;                       // 8192

  float* out      = (float*)d_out;
  float* out_xq   = out;                 // 2097152
  float* out_loss = out + NELEM;         // 1
  float* out_idx  = out + NELEM + 1;     // 32768

  vq_sc<<<N_E / 256, 256, 0, stream>>>(cb, sc);
  dim3 g1(NTOK / TM, N_E / TN);
  vq_pass1<<<g1, 256, 0, stream>>>(x, cb, sc, minima, p_start, p_end);
  vq_select<<<NTOK / 256, 256, 0, stream>>>(x, cb, sc, minima, bestidx, p_start, p_end);
  vq_combine<<<NTOK / 4, 256, 0, stream>>>(x, cb, bestidx, out_xq, out_idx, partial);
  vq_loss<<<1, 256, 0, stream>>>(partial, out_loss);
}

// Round 4
// 690.985 us; speedup vs baseline: 10.1703x; 10.1703x over previous
//
#include <hip/hip_runtime.h>
#include <math.h>

// VectorQuantizer: x (32768,64) f32, codebook (8192,64) f32, start/end/use_sk ints.
// Outputs concat: x_q_st (2097152 f32) | loss (1 f32) | indices (32768 as f32 values).
//
// Architecture (R3 concept validated absmax 0.0, R4 fixes the mappings):
//  Pass 1 (vq_pass1): fp32-FMA tiled GEMM, g_k = sc_k - 2*dot(x,c_k); per-(token,
//    128-code chunk) min -> minima[token][chunk] (token-major, coalesced rescue reads).
//    FMA fine here: |g_fma - g_numpy| < ~1e-8 while reference d carries <=7.6e-6
//    rounding slop (ulp@64); window W=1e-4 gives 6x margin. Validated in R3.
//  Pass 2 (vq_rescue): WAVE per token. Lane=chunk reads minima row (coalesced 256B),
//    butterfly min -> thresh, __ballot -> wave-uniform flagged-chunk mask. Cooperative
//    exact rescan: lane evaluates 2 of the 128 codes with the BIT-EXACT numpy-replica
//    arithmetic validated in R1 (pairwise-8, separate mul+add); lex-min on packed
//    (enc(d), k) == strict-< ascending-k first-occurrence. Same wave does gather +
//    x_q_st + loss partial (replaces vq_combine).
// DO NOT change the exact-path arithmetic: inter-code d gaps are ~1 ulp of d.

#define N_E    8192
#define EDIM   64
#define NTOK   32768
#define NELEM  (NTOK * EDIM)       // 2097152
#define TM     128                 // pass-1 token tile
#define TN     128                 // pass-1 code tile == chunk
#define NCHUNK (N_E / TN)          // 64 chunks
#define WINDOW 1e-4f

// ---------------- k1: codebook squared norms (np.sum pairwise-8 replica) -------------
__global__ __launch_bounds__(256) void vq_sc(const float* __restrict__ cb,
                                             float* __restrict__ sc) {
#pragma clang fp contract(off)
  int r = blockIdx.x * 256 + threadIdx.x;
  const float4* c4 = (const float4*)(cb + (size_t)r * EDIM);
  float a[8];
#pragma unroll
  for (int j = 0; j < 8; ++j) a[j] = 0.0f;
#pragma unroll
  for (int i = 0; i < 8; ++i) {
    float4 pA = c4[2*i], pB = c4[2*i+1];
    a[0] += pA.x * pA.x; a[1] += pA.y * pA.y; a[2] += pA.z * pA.z; a[3] += pA.w * pA.w;
    a[4] += pB.x * pB.x; a[5] += pB.y * pB.y; a[6] += pB.z * pB.z; a[7] += pB.w * pB.w;
  }
  sc[r] = ((a[0]+a[1]) + (a[2]+a[3])) + ((a[4]+a[5]) + (a[6]+a[7]));
}

// ---------------- pass 1: approximate GEMM + per-chunk minima ------------------------
// Block tile: 128 tokens x 128 codes, K=64 in LDS (k-major). Micro-tile 8x8:
// 64 FMA per 4 ds_read_b128. tx=tid&15 -> codes, ty=tid>>4 -> tokens.
__global__ __launch_bounds__(256, 2) void vq_pass1(
    const float* __restrict__ x, const float* __restrict__ cb,
    const float* __restrict__ sc, float* __restrict__ minima,
    const int* __restrict__ p_start, const int* __restrict__ p_end) {
  __shared__ float Xs[64][132];   // [k][token], 132: k-rows rotate banks by 4
  __shared__ float Cs[64][132];   // [k][code]
  int tid = threadIdx.x;
  int tb = blockIdx.x;            // token tile [0, 256)
  int nb = blockIdx.y;            // code tile / chunk [0, 64)
  const float4* xg = (const float4*)(x  + (size_t)tb * TM * EDIM);
  const float4* cg = (const float4*)(cb + (size_t)nb * TN * EDIM);

  // Stage both tiles: 128 rows x 16 float4 each, coalesced global, transpose into LDS.
#pragma unroll
  for (int p = 0; p < 8; ++p) {
    int idx = tid + p * 256;          // [0, 2048)
    int m = idx >> 4, j = idx & 15;
    float4 v = xg[idx];
    Xs[4*j+0][m] = v.x; Xs[4*j+1][m] = v.y; Xs[4*j+2][m] = v.z; Xs[4*j+3][m] = v.w;
  }
#pragma unroll
  for (int p = 0; p < 8; ++p) {
    int idx = tid + p * 256;
    int n = idx >> 4, j = idx & 15;
    float4 v = cg[idx];
    Cs[4*j+0][n] = v.x; Cs[4*j+1][n] = v.y; Cs[4*j+2][n] = v.z; Cs[4*j+3][n] = v.w;
  }
  __syncthreads();

  int tx = tid & 15, ty = tid >> 4;
  int m0 = ty * 8, n0 = tx * 8;
  float acc[8][8];
#pragma unroll
  for (int i = 0; i < 8; ++i)
#pragma unroll
    for (int j = 0; j < 8; ++j) acc[i][j] = 0.0f;

#pragma unroll 2
  for (int k = 0; k < 64; ++k) {
    float4 xv0 = *(const float4*)&Xs[k][m0];
    float4 xv1 = *(const float4*)&Xs[k][m0 + 4];
    float4 cv0 = *(const float4*)&Cs[k][n0];
    float4 cv1 = *(const float4*)&Cs[k][n0 + 4];
    float xsv[8] = {xv0.x, xv0.y, xv0.z, xv0.w, xv1.x, xv1.y, xv1.z, xv1.w};
    float csv[8] = {cv0.x, cv0.y, cv0.z, cv0.w, cv1.x, cv1.y, cv1.z, cv1.w};
#pragma unroll
    for (int i = 0; i < 8; ++i)
#pragma unroll
      for (int j = 0; j < 8; ++j) acc[i][j] = fmaf(xsv[i], csv[j], acc[i][j]);
  }

  __syncthreads();                 // Xs reads done; reuse Xs as reduction scratch
  float* sred = &Xs[0][0];         // 128 tokens x 16 lanes, stride 17
  int s = *p_start, e = *p_end;
  float4 sa = *(const float4*)&sc[nb * TN + n0];
  float4 sb = *(const float4*)&sc[nb * TN + n0 + 4];
  float scv[8] = {sa.x, sa.y, sa.z, sa.w, sb.x, sb.y, sb.z, sb.w};
#pragma unroll
  for (int i = 0; i < 8; ++i) {
    float v = INFINITY;
#pragma unroll
    for (int j = 0; j < 8; ++j) {
      int gk = nb * TN + n0 + j;
      float g = scv[j] - 2.0f * acc[i][j];
      if (gk >= s && gk < e) v = fminf(v, g);
    }
    sred[(m0 + i) * 17 + tx] = v;
  }
  __syncthreads();
  if (tid < TM) {
    float v = INFINITY;
#pragma unroll
    for (int t = 0; t < 16; ++t) v = fminf(v, sred[tid * 17 + t]);
    minima[(size_t)(tb * TM + tid) * NCHUNK + nb] = v;   // token-major
  }
}

// ---------------- pass 2: cooperative exact rescue + epilogue ------------------------
// Wave per token (4 waves/block). Bit-exact numpy-replica d on flagged chunks.
__global__ __launch_bounds__(256) void vq_rescue(
    const float* __restrict__ x, const float* __restrict__ cb,
    const float* __restrict__ sc, const float* __restrict__ minima,
    float* __restrict__ out_xq, float* __restrict__ out_idx,
    float* __restrict__ partial,
    const int* __restrict__ p_start, const int* __restrict__ p_end) {
#pragma clang fp contract(off)
  int tid  = threadIdx.x;
  int wv   = tid >> 6;
  int lane = tid & 63;
  int token = blockIdx.x * 4 + wv;

  __shared__ float xs[4][64];
  float xx = x[(size_t)token * EDIM + lane];   // coalesced row load
  xs[wv][lane] = xx;
  __syncthreads();
  const float4* xl4 = (const float4*)xs[wv];   // broadcast reads: conflict-free

  // sx = np.sum(x*x) pairwise-8 replica (all lanes compute identical value)
  float a[8];
#pragma unroll
  for (int j = 0; j < 8; ++j) a[j] = 0.0f;
#pragma unroll
  for (int i = 0; i < 8; ++i) {
    float4 pA = xl4[2*i], pB = xl4[2*i+1];
    a[0] += pA.x * pA.x; a[1] += pA.y * pA.y; a[2] += pA.z * pA.z; a[3] += pA.w * pA.w;
    a[4] += pB.x * pB.x; a[5] += pB.y * pB.y; a[6] += pB.z * pB.z; a[7] += pB.w * pB.w;
  }
  float sx = ((a[0]+a[1]) + (a[2]+a[3])) + ((a[4]+a[5]) + (a[6]+a[7]));

  // lane = chunk: coalesced minima row, butterfly min, ballot -> flagged mask
  float mv = minima[(size_t)token * NCHUNK + lane];
  float m = mv;
#pragma unroll
  for (int off = 32; off >= 1; off >>= 1) m = fminf(m, __shfl_xor(m, off, 64));
  unsigned long long flagged = __ballot(mv <= m + WINDOW);

  int s = *p_start, e = *p_end;
  unsigned long long bestpack = ~0ull;

  while (flagged) {
    int c = __ffsll(flagged) - 1;
    flagged &= flagged - 1;
    int kb = c * TN;
#pragma unroll
    for (int u = 0; u < 2; ++u) {
      int k = kb + 2 * lane + u;
      if (k >= s && k < e) {
        const float4* c4 = (const float4*)(cb + (size_t)k * EDIM);
        float t[8];
#pragma unroll
        for (int j = 0; j < 8; ++j) t[j] = 0.0f;
#pragma unroll
        for (int i = 0; i < 8; ++i) {     // elements 8i..8i+7, i ascending (= R1 order)
          float4 cA = c4[2*i], cB = c4[2*i+1];
          float4 pA = xl4[2*i], pB = xl4[2*i+1];
          t[0] += cA.x * pA.x; t[1] += cA.y * pA.y;
          t[2] += cA.z * pA.z; t[3] += cA.w * pA.w;
          t[4] += cB.x * pB.x; t[5] += cB.y * pB.y;
          t[6] += cB.z * pB.z; t[7] += cB.w * pB.w;
        }
        float tt = ((t[0]+t[1]) + (t[2]+t[3])) + ((t[4]+t[5]) + (t[6]+t[7]));
        float d = (sx + sc[k]) - 2.0f * tt;
        unsigned int db = __float_as_uint(d);
        unsigned int en = db ^ ((unsigned int)((int)db >> 31) | 0x80000000u);
        unsigned long long pk = ((unsigned long long)en << 32) | (unsigned int)k;
        if (pk < bestpack) bestpack = pk;
      }
    }
  }
  // lex-min reduce: (d asc, k asc) == numpy first-occurrence argmin
#pragma unroll
  for (int off = 32; off >= 1; off >>= 1) {
    unsigned long long o = __shfl_xor(bestpack, off, 64);
    if (o < bestpack) bestpack = o;
  }
  int bidx = (int)(unsigned int)(bestpack & 0xFFFFFFFFull);

  // epilogue: gather chosen code, x_q_st, index, loss partial (as validated R1)
  float q = cb[(size_t)bidx * EDIM + lane];
  float diff = q - xx;                              // fl(x_q - x)
  out_xq[(size_t)token * EDIM + lane] = xx + diff;  // fl(x + fl(x_q - x))
  if (lane == 0) out_idx[token] = (float)bidx;

  float l = diff * diff;
#pragma unroll
  for (int off = 32; off >= 1; off >>= 1) l += __shfl_down(l, off, 64);
  __shared__ float sdata[4];
  if (lane == 0) sdata[wv] = l;
  __syncthreads();
  if (tid == 0) partial[blockIdx.x] = (sdata[0] + sdata[1]) + (sdata[2] + sdata[3]);
}

// ---------------- k4: final loss reduction -------------------------------------------
__global__ __launch_bounds__(256) void vq_loss(const float* __restrict__ partial,
                                               float* __restrict__ out_loss) {
  int tid = threadIdx.x;
  float s = 0.0f;
  for (int i = tid; i < NTOK / 4; i += 256) s += partial[i];
#pragma unroll
  for (int off = 32; off >= 1; off >>= 1) s += __shfl_down(s, off, 64);
  __shared__ float sdata[4];
  if ((tid & 63) == 0) sdata[tid >> 6] = s;
  __syncthreads();
  if (tid == 0) {
    float total = (sdata[0] + sdata[1]) + (sdata[2] + sdata[3]);
    float m = total * (1.0f / (float)NELEM);
    out_loss[0] = m + 0.25f * m;
  }
}

// ---------------- launch -------------------------------------------------------------
extern "C" void kernel_launch(void* const* d_in, const int* in_sizes, int n_in,
                              void* d_out, int out_size, void* d_ws, size_t ws_size,
                              hipStream_t stream) {
  const float* x  = (const float*)d_in[0];
  const float* cb = (const float*)d_in[1];
  const int* p_start = (const int*)d_in[2];
  const int* p_end   = (const int*)d_in[3];

  float* ws = (float*)d_ws;
  float* sc      = ws;                                   // 8192
  float* minima  = ws + N_E;                             // 32768*64 floats (8 MB)
  float* partial = minima + (size_t)NTOK * NCHUNK;       // 8192

  float* out      = (float*)d_out;
  float* out_xq   = out;                 // 2097152
  float* out_loss = out + NELEM;         // 1
  float* out_idx  = out + NELEM + 1;     // 32768

  vq_sc<<<N_E / 256, 256, 0, stream>>>(cb, sc);
  dim3 g1(NTOK / TM, N_E / TN);
  vq_pass1<<<g1, 256, 0, stream>>>(x, cb, sc, minima, p_start, p_end);
  vq_rescue<<<NTOK / 4, 256, 0, stream>>>(x, cb, sc, minima, out_xq, out_idx,
                                          partial, p_start, p_end);
  vq_loss<<<1, 256, 0, stream>>>(partial, out_loss);
}

// Round 5
// 514.643 us; speedup vs baseline: 13.6551x; 1.3426x over previous
//
#include <hip/hip_runtime.h>
#include <math.h>

// VectorQuantizer: x (32768,64) f32, codebook (8192,64) f32, start/end/use_sk ints.
// Outputs concat: x_q_st (2097152 f32) | loss (1 f32) | indices (32768 as f32 values).
//
// R5 architecture: bf16-MFMA filter + bit-exact rescue.
//  vq_prep:  x -> xbf (bf16 RTNE).      vq_sc: sc_k exact (pairwise-8) + cb -> cbf.
//  vq_pass1: bf16 MFMA GEMM (16x16x32), g_k = sc_k - 2*dot_bf16(x,c_k); per-(token,
//    64-code chunk) min stored as f16. Error |g_bf - g_exact| <= 3.6e-5 worst case
//    (2*2^-9*sum|x_i|*max|c|), f16 store adds <=1.6e-5; WINDOW=5e-4 covers 2x error
//    + the reference's own 7.6e-6 rounding slop with >5x margin.
//  vq_rescue: wave/token. Coalesced f16 minima row, butterfly min -> thresh, ballot ->
//    flagged chunks; lane evaluates 1 code/chunk with the BIT-EXACT numpy-replica
//    arithmetic validated in R1 (pairwise-8, separate mul+add); lex-min on packed
//    (enc(d), k) == strict-< ascending-k first-occurrence. Epilogue fused.
// Exactness: true first-argmin k* satisfies g_bf(k*) <= min_bf + 2*err < min_bf + W,
// so its chunk is always flagged; rescue's exact lex-min over that superset is
// bit-identical to numpy. DO NOT change the exact-path arithmetic.

#define N_E    8192
#define EDIM   64
#define NTOK   32768
#define NELEM  (NTOK * EDIM)
#define TM     128                 // pass-1 token tile
#define TN     128                 // pass-1 code tile (= 2 chunks)
#define CSZ    64                  // chunk size
#define NCHUNK (N_E / CSZ)         // 128 chunks
#define WINDOW 5e-4f
#define LROW   72                  // LDS row stride in ushorts (144 B): uniform banks

typedef __attribute__((ext_vector_type(8))) short          short8;
typedef __attribute__((ext_vector_type(8))) unsigned short ushort8v;
typedef __attribute__((ext_vector_type(4))) unsigned short ushort4v;
typedef __attribute__((ext_vector_type(4))) float          f32x4;

__device__ __forceinline__ unsigned short f2bf(float f) {   // RTNE f32->bf16 bits
  unsigned int u = __float_as_uint(f);
  return (unsigned short)((u + 0x7FFFu + ((u >> 16) & 1u)) >> 16);
}
__device__ __forceinline__ unsigned short f2h(float f) {
  union { _Float16 h; unsigned short u; } cv; cv.h = (_Float16)f; return cv.u;
}
__device__ __forceinline__ float h2f(unsigned short b) {
  union { _Float16 h; unsigned short u; } cv; cv.u = b; return (float)cv.h;
}

// ---------------- prep: x -> bf16 ----------------------------------------------------
__global__ __launch_bounds__(256) void vq_prep(const float* __restrict__ x,
                                               unsigned short* __restrict__ xbf) {
  int i = blockIdx.x * 256 + threadIdx.x;        // float4 index
  float4 f = ((const float4*)x)[i];
  ushort4v o = {f2bf(f.x), f2bf(f.y), f2bf(f.z), f2bf(f.w)};
  ((ushort4v*)xbf)[i] = o;
}

// ---------------- sc (exact pairwise-8) + cb -> bf16 ---------------------------------
__global__ __launch_bounds__(256) void vq_sc(const float* __restrict__ cb,
                                             float* __restrict__ sc,
                                             unsigned short* __restrict__ cbf) {
#pragma clang fp contract(off)
  int r = blockIdx.x * 256 + threadIdx.x;
  const float4* c4 = (const float4*)(cb + (size_t)r * EDIM);
  float a[8];
#pragma unroll
  for (int j = 0; j < 8; ++j) a[j] = 0.0f;
#pragma unroll
  for (int i = 0; i < 8; ++i) {
    float4 pA = c4[2*i], pB = c4[2*i+1];
    a[0] += pA.x * pA.x; a[1] += pA.y * pA.y; a[2] += pA.z * pA.z; a[3] += pA.w * pA.w;
    a[4] += pB.x * pB.x; a[5] += pB.y * pB.y; a[6] += pB.z * pB.z; a[7] += pB.w * pB.w;
  }
  sc[r] = ((a[0]+a[1]) + (a[2]+a[3])) + ((a[4]+a[5]) + (a[6]+a[7]));
  ushort4v* dst = (ushort4v*)(cbf + (size_t)r * EDIM);
#pragma unroll
  for (int j = 0; j < 16; ++j) {
    float4 f = c4[j];
    ushort4v o = {f2bf(f.x), f2bf(f.y), f2bf(f.z), f2bf(f.w)};
    dst[j] = o;
  }
}

// ---------------- pass 1: bf16 MFMA filter + per-chunk minima ------------------------
// Block: 128 tokens x 128 codes, K=64. 4 waves; wave wv covers tokens wv*32..+31.
// Frags (verified gfx950 layout): A[m=lane&15][k=quad*8+j], B[n=lane&15][k same],
// D: col=lane&15, row=quad*4+reg.
__global__ __launch_bounds__(256, 4) void vq_pass1(
    const unsigned short* __restrict__ xbf, const unsigned short* __restrict__ cbf,
    const float* __restrict__ sc, unsigned short* __restrict__ minima,
    const int* __restrict__ p_start, const int* __restrict__ p_end) {
  __shared__ unsigned short Xs[TM * LROW];   // 18432 B
  __shared__ unsigned short Cs[TN * LROW];   // 18432 B
  int tid = threadIdx.x;
  int tb = blockIdx.x, nb = blockIdx.y;
  const ushort8v* xg = (const ushort8v*)(xbf + (size_t)tb * TM * EDIM);
  const ushort8v* cg = (const ushort8v*)(cbf + (size_t)nb * TN * EDIM);
#pragma unroll
  for (int p = 0; p < 4; ++p) {              // 1024 ushort8 per array, coalesced
    int idx = tid + p * 256;
    int n = idx >> 3, h = idx & 7;
    *(ushort8v*)&Xs[n * LROW + h * 8] = xg[idx];
    *(ushort8v*)&Cs[n * LROW + h * 8] = cg[idx];
  }
  __syncthreads();

  int lane = tid & 63, wv = tid >> 6;
  int q = lane >> 4, ln = lane & 15;
  f32x4 acc[2][8];
#pragma unroll
  for (int t = 0; t < 2; ++t)
#pragma unroll
    for (int c = 0; c < 8; ++c) acc[t][c] = (f32x4)0.0f;

#pragma unroll
  for (int ks = 0; ks < 2; ++ks) {
    int ko = ks * 32 + q * 8;
    short8 a0 = *(const short8*)&Xs[(wv * 32 + ln) * LROW + ko];
    short8 a1 = *(const short8*)&Xs[(wv * 32 + 16 + ln) * LROW + ko];
#pragma unroll
    for (int c = 0; c < 8; ++c) {
      short8 b = *(const short8*)&Cs[(c * 16 + ln) * LROW + ko];
      acc[0][c] = __builtin_amdgcn_mfma_f32_16x16x32_bf16(a0, b, acc[0][c], 0, 0, 0);
      acc[1][c] = __builtin_amdgcn_mfma_f32_16x16x32_bf16(a1, b, acc[1][c], 0, 0, 0);
    }
  }

  int s = *p_start, e = *p_end;
  float gmin[2][4][2];
#pragma unroll
  for (int t = 0; t < 2; ++t)
#pragma unroll
    for (int r = 0; r < 4; ++r) { gmin[t][r][0] = INFINITY; gmin[t][r][1] = INFINITY; }
#pragma unroll
  for (int c = 0; c < 8; ++c) {
    int code = nb * TN + c * 16 + ln;
    float scv = sc[code];
    bool ok = (code >= s) && (code < e);
    int hf = c >> 2;                         // chunk half: c 0..3 -> 0, 4..7 -> 1
#pragma unroll
    for (int t = 0; t < 2; ++t)
#pragma unroll
      for (int r = 0; r < 4; ++r) {
        float g = scv - 2.0f * acc[t][c][r];
        if (ok) gmin[t][r][hf] = fminf(gmin[t][r][hf], g);
      }
  }
#pragma unroll
  for (int off = 8; off >= 1; off >>= 1)     // xor<=8 stays within 16-lane group
#pragma unroll
    for (int t = 0; t < 2; ++t)
#pragma unroll
      for (int r = 0; r < 4; ++r) {
        gmin[t][r][0] = fminf(gmin[t][r][0], __shfl_xor(gmin[t][r][0], off, 64));
        gmin[t][r][1] = fminf(gmin[t][r][1], __shfl_xor(gmin[t][r][1], off, 64));
      }

  __syncthreads();                           // done with Xs; reuse as bounce buffer
  float* sred = (float*)Xs;                  // 128 tokens x 2 halves
  if (ln == 0) {
#pragma unroll
    for (int t = 0; t < 2; ++t)
#pragma unroll
      for (int r = 0; r < 4; ++r) {
        int tl = wv * 32 + t * 16 + q * 4 + r;
        sred[tl * 2 + 0] = gmin[t][r][0];
        sred[tl * 2 + 1] = gmin[t][r][1];
      }
  }
  __syncthreads();
  if (tid < TM) {
    unsigned int pk = (unsigned int)f2h(sred[tid * 2])
                    | ((unsigned int)f2h(sred[tid * 2 + 1]) << 16);
    *(unsigned int*)(minima + (size_t)(tb * TM + tid) * NCHUNK + nb * 2) = pk;
  }
}

// ---------------- pass 2: cooperative exact rescue + epilogue ------------------------
__global__ __launch_bounds__(256) void vq_rescue(
    const float* __restrict__ x, const float* __restrict__ cb,
    const float* __restrict__ sc, const unsigned short* __restrict__ minima,
    float* __restrict__ out_xq, float* __restrict__ out_idx,
    float* __restrict__ partial,
    const int* __restrict__ p_start, const int* __restrict__ p_end) {
#pragma clang fp contract(off)
  int tid  = threadIdx.x;
  int wv   = tid >> 6;
  int lane = tid & 63;
  int token = blockIdx.x * 4 + wv;

  __shared__ float xs[4][64];
  float xx = x[(size_t)token * EDIM + lane];
  xs[wv][lane] = xx;
  __syncthreads();
  const float4* xl4 = (const float4*)xs[wv];

  // sx = np.sum(x*x) pairwise-8 replica
  float a[8];
#pragma unroll
  for (int j = 0; j < 8; ++j) a[j] = 0.0f;
#pragma unroll
  for (int i = 0; i < 8; ++i) {
    float4 pA = xl4[2*i], pB = xl4[2*i+1];
    a[0] += pA.x * pA.x; a[1] += pA.y * pA.y; a[2] += pA.z * pA.z; a[3] += pA.w * pA.w;
    a[4] += pB.x * pB.x; a[5] += pB.y * pB.y; a[6] += pB.z * pB.z; a[7] += pB.w * pB.w;
  }
  float sx = ((a[0]+a[1]) + (a[2]+a[3])) + ((a[4]+a[5]) + (a[6]+a[7]));

  // minima row: lane covers chunks {2*lane, 2*lane+1} (one coalesced dword each)
  unsigned int u = *(const unsigned int*)(minima + (size_t)token * NCHUNK + lane * 2);
  float mv0 = h2f((unsigned short)(u & 0xFFFFu));
  float mv1 = h2f((unsigned short)(u >> 16));
  float m = fminf(mv0, mv1);
#pragma unroll
  for (int off = 32; off >= 1; off >>= 1) m = fminf(m, __shfl_xor(m, off, 64));
  float thr = m + WINDOW;
  unsigned long long f0 = __ballot(mv0 <= thr);
  unsigned long long f1 = __ballot(mv1 <= thr);

  int s = *p_start, e = *p_end;
  unsigned long long bestpack = ~0ull;
#pragma unroll
  for (int half = 0; half < 2; ++half) {
    unsigned long long fm = half ? f1 : f0;
    while (fm) {
      int c = __ffsll((long long)fm) - 1;
      fm &= fm - 1;
      int k = (2 * c + half) * CSZ + lane;   // 64 codes, 1 per lane
      if (k >= s && k < e) {
        const float4* c4 = (const float4*)(cb + (size_t)k * EDIM);
        float t[8];
#pragma unroll
        for (int j = 0; j < 8; ++j) t[j] = 0.0f;
#pragma unroll
        for (int i = 0; i < 8; ++i) {        // elements 8i..8i+7, i ascending (R1 order)
          float4 cA = c4[2*i], cB = c4[2*i+1];
          float4 pA = xl4[2*i], pB = xl4[2*i+1];
          t[0] += cA.x * pA.x; t[1] += cA.y * pA.y;
          t[2] += cA.z * pA.z; t[3] += cA.w * pA.w;
          t[4] += cB.x * pB.x; t[5] += cB.y * pB.y;
          t[6] += cB.z * pB.z; t[7] += cB.w * pB.w;
        }
        float tt = ((t[0]+t[1]) + (t[2]+t[3])) + ((t[4]+t[5]) + (t[6]+t[7]));
        float d = (sx + sc[k]) - 2.0f * tt;
        unsigned int db = __float_as_uint(d);
        unsigned int en = db ^ ((unsigned int)((int)db >> 31) | 0x80000000u);
        unsigned long long pk = ((unsigned long long)en << 32) | (unsigned int)k;
        if (pk < bestpack) bestpack = pk;
      }
    }
  }
#pragma unroll
  for (int off = 32; off >= 1; off >>= 1) {
    unsigned long long o = __shfl_xor(bestpack, off, 64);
    if (o < bestpack) bestpack = o;
  }
  int bidx = (int)(unsigned int)(bestpack & 0xFFFFFFFFull);

  float qv = cb[(size_t)bidx * EDIM + lane];
  float diff = qv - xx;                              // fl(x_q - x)
  out_xq[(size_t)token * EDIM + lane] = xx + diff;   // fl(x + fl(x_q - x))
  if (lane == 0) out_idx[token] = (float)bidx;

  float l = diff * diff;
#pragma unroll
  for (int off = 32; off >= 1; off >>= 1) l += __shfl_down(l, off, 64);
  __shared__ float sdata[4];
  if (lane == 0) sdata[wv] = l;
  __syncthreads();
  if (tid == 0) partial[blockIdx.x] = (sdata[0] + sdata[1]) + (sdata[2] + sdata[3]);
}

// ---------------- final loss reduction ----------------------------------------------
__global__ __launch_bounds__(256) void vq_loss(const float* __restrict__ partial,
                                               float* __restrict__ out_loss) {
  int tid = threadIdx.x;
  float s = 0.0f;
  for (int i = tid; i < NTOK / 4; i += 256) s += partial[i];
#pragma unroll
  for (int off = 32; off >= 1; off >>= 1) s += __shfl_down(s, off, 64);
  __shared__ float sdata[4];
  if ((tid & 63) == 0) sdata[tid >> 6] = s;
  __syncthreads();
  if (tid == 0) {
    float total = (sdata[0] + sdata[1]) + (sdata[2] + sdata[3]);
    float m = total * (1.0f / (float)NELEM);
    out_loss[0] = m + 0.25f * m;
  }
}

// ---------------- launch -------------------------------------------------------------
extern "C" void kernel_launch(void* const* d_in, const int* in_sizes, int n_in,
                              void* d_out, int out_size, void* d_ws, size_t ws_size,
                              hipStream_t stream) {
  const float* x  = (const float*)d_in[0];
  const float* cb = (const float*)d_in[1];
  const int* p_start = (const int*)d_in[2];
  const int* p_end   = (const int*)d_in[3];

  float* ws = (float*)d_ws;
  float* sc      = ws;                                    // 8192 f
  float* partial = ws + N_E;                              // 8192 f
  unsigned short* xbf    = (unsigned short*)(ws + 2 * N_E);   // 2097152 us (4 MB)
  unsigned short* cbf    = xbf + (size_t)NTOK * EDIM;         // 524288 us (1 MB)
  unsigned short* minima = cbf + (size_t)N_E * EDIM;          // 32768*128 us (8 MB)

  float* out      = (float*)d_out;
  float* out_xq   = out;                 // 2097152
  float* out_loss = out + NELEM;         // 1
  float* out_idx  = out + NELEM + 1;     // 32768

  vq_prep<<<NELEM / 1024, 256, 0, stream>>>(x, xbf);
  vq_sc<<<N_E / 256, 256, 0, stream>>>(cb, sc, cbf);
  dim3 g1(NTOK / TM, N_E / TN);
  vq_pass1<<<g1, 256, 0, stream>>>(xbf, cbf, sc, minima, p_start, p_end);
  vq_rescue<<<NTOK / 4, 256, 0, stream>>>(x, cb, sc, minima, out_xq, out_idx,
                                          partial, p_start, p_end);
  vq_loss<<<1, 256, 0, stream>>>(partial, out_loss);
}

// Round 6
// 291.653 us; speedup vs baseline: 24.0954x; 1.7646x over previous
//
#include <hip/hip_runtime.h>
#include <math.h>

// VectorQuantizer: x (32768,64) f32, codebook (8192,64) f32, start/end/use_sk ints.
// Outputs concat: x_q_st (2097152 f32) | loss (1 f32) | indices (32768 as f32 values).
//
// R6 architecture: bf16-MFMA filter + bit-exact rescue (R5, validated absmax 0.0),
// with the rescue gather fixed: per flagged chunk the wave stages the chunk's 16KB
// cooperatively (coalesced dwordx4) into a padded per-wave LDS buffer (stride 68
// floats = 272B: 16B-aligned b128, even 8-lanes-per-bank-quad spread = inherent
// throughput, no conflict penalty), then each lane evaluates its row from LDS with
// the BYTE-IDENTICAL R1 numpy-replica arithmetic.
// WINDOW 5e-4 -> 3e-4: rigorous filter-error bound = 2*bf16_dot_err (<=2*6.1e-5,
// Cauchy-Schwarz with ||x||<=12, ||c||<=6.5e-4) + 2*f16_store_ulp (1.5e-5) +
// reference d-slop (1.5e-5) ~= 1.5e-4; 3e-4 keeps 2x margin.
// Exactness: true argmin's chunk always flagged; exact lex-min over superset ==
// numpy strict-< ascending-k first-occurrence. DO NOT change exact-path arithmetic.

#define N_E    8192
#define EDIM   64
#define NTOK   32768
#define NELEM  (NTOK * EDIM)
#define TM     128                 // pass-1 token tile
#define TN     128                 // pass-1 code tile (= 2 chunks)
#define CSZ    64                  // chunk size
#define NCHUNK (N_E / CSZ)         // 128 chunks
#define WINDOW 3e-4f
#define LROW   72                  // pass-1 LDS row stride (ushorts)
#define RSTRIDE 68                 // rescue LDS row stride (floats, 272B)

typedef __attribute__((ext_vector_type(8))) short          short8;
typedef __attribute__((ext_vector_type(8))) unsigned short ushort8v;
typedef __attribute__((ext_vector_type(4))) unsigned short ushort4v;
typedef __attribute__((ext_vector_type(4))) float          f32x4;

__device__ __forceinline__ unsigned short f2bf(float f) {   // RTNE f32->bf16 bits
  unsigned int u = __float_as_uint(f);
  return (unsigned short)((u + 0x7FFFu + ((u >> 16) & 1u)) >> 16);
}
__device__ __forceinline__ unsigned short f2h(float f) {
  union { _Float16 h; unsigned short u; } cv; cv.h = (_Float16)f; return cv.u;
}
__device__ __forceinline__ float h2f(unsigned short b) {
  union { _Float16 h; unsigned short u; } cv; cv.u = b; return (float)cv.h;
}

// ---------------- prep: x -> bf16 ----------------------------------------------------
__global__ __launch_bounds__(256) void vq_prep(const float* __restrict__ x,
                                               unsigned short* __restrict__ xbf) {
  int i = blockIdx.x * 256 + threadIdx.x;
  float4 f = ((const float4*)x)[i];
  ushort4v o = {f2bf(f.x), f2bf(f.y), f2bf(f.z), f2bf(f.w)};
  ((ushort4v*)xbf)[i] = o;
}

// ---------------- sc (exact pairwise-8) + cb -> bf16 ---------------------------------
__global__ __launch_bounds__(256) void vq_sc(const float* __restrict__ cb,
                                             float* __restrict__ sc,
                                             unsigned short* __restrict__ cbf) {
#pragma clang fp contract(off)
  int r = blockIdx.x * 256 + threadIdx.x;
  const float4* c4 = (const float4*)(cb + (size_t)r * EDIM);
  float a[8];
#pragma unroll
  for (int j = 0; j < 8; ++j) a[j] = 0.0f;
#pragma unroll
  for (int i = 0; i < 8; ++i) {
    float4 pA = c4[2*i], pB = c4[2*i+1];
    a[0] += pA.x * pA.x; a[1] += pA.y * pA.y; a[2] += pA.z * pA.z; a[3] += pA.w * pA.w;
    a[4] += pB.x * pB.x; a[5] += pB.y * pB.y; a[6] += pB.z * pB.z; a[7] += pB.w * pB.w;
  }
  sc[r] = ((a[0]+a[1]) + (a[2]+a[3])) + ((a[4]+a[5]) + (a[6]+a[7]));
  ushort4v* dst = (ushort4v*)(cbf + (size_t)r * EDIM);
#pragma unroll
  for (int j = 0; j < 16; ++j) {
    float4 f = c4[j];
    ushort4v o = {f2bf(f.x), f2bf(f.y), f2bf(f.z), f2bf(f.w)};
    dst[j] = o;
  }
}

// ---------------- pass 1: bf16 MFMA filter + per-chunk minima (unchanged R5) ---------
__global__ __launch_bounds__(256, 4) void vq_pass1(
    const unsigned short* __restrict__ xbf, const unsigned short* __restrict__ cbf,
    const float* __restrict__ sc, unsigned short* __restrict__ minima,
    const int* __restrict__ p_start, const int* __restrict__ p_end) {
  __shared__ unsigned short Xs[TM * LROW];
  __shared__ unsigned short Cs[TN * LROW];
  int tid = threadIdx.x;
  int tb = blockIdx.x, nb = blockIdx.y;
  const ushort8v* xg = (const ushort8v*)(xbf + (size_t)tb * TM * EDIM);
  const ushort8v* cg = (const ushort8v*)(cbf + (size_t)nb * TN * EDIM);
#pragma unroll
  for (int p = 0; p < 4; ++p) {
    int idx = tid + p * 256;
    int n = idx >> 3, h = idx & 7;
    *(ushort8v*)&Xs[n * LROW + h * 8] = xg[idx];
    *(ushort8v*)&Cs[n * LROW + h * 8] = cg[idx];
  }
  __syncthreads();

  int lane = tid & 63, wv = tid >> 6;
  int q = lane >> 4, ln = lane & 15;
  f32x4 acc[2][8];
#pragma unroll
  for (int t = 0; t < 2; ++t)
#pragma unroll
    for (int c = 0; c < 8; ++c) acc[t][c] = (f32x4)0.0f;

#pragma unroll
  for (int ks = 0; ks < 2; ++ks) {
    int ko = ks * 32 + q * 8;
    short8 a0 = *(const short8*)&Xs[(wv * 32 + ln) * LROW + ko];
    short8 a1 = *(const short8*)&Xs[(wv * 32 + 16 + ln) * LROW + ko];
#pragma unroll
    for (int c = 0; c < 8; ++c) {
      short8 b = *(const short8*)&Cs[(c * 16 + ln) * LROW + ko];
      acc[0][c] = __builtin_amdgcn_mfma_f32_16x16x32_bf16(a0, b, acc[0][c], 0, 0, 0);
      acc[1][c] = __builtin_amdgcn_mfma_f32_16x16x32_bf16(a1, b, acc[1][c], 0, 0, 0);
    }
  }

  int s = *p_start, e = *p_end;
  float gmin[2][4][2];
#pragma unroll
  for (int t = 0; t < 2; ++t)
#pragma unroll
    for (int r = 0; r < 4; ++r) { gmin[t][r][0] = INFINITY; gmin[t][r][1] = INFINITY; }
#pragma unroll
  for (int c = 0; c < 8; ++c) {
    int code = nb * TN + c * 16 + ln;
    float scv = sc[code];
    bool ok = (code >= s) && (code < e);
    int hf = c >> 2;
#pragma unroll
    for (int t = 0; t < 2; ++t)
#pragma unroll
      for (int r = 0; r < 4; ++r) {
        float g = scv - 2.0f * acc[t][c][r];
        if (ok) gmin[t][r][hf] = fminf(gmin[t][r][hf], g);
      }
  }
#pragma unroll
  for (int off = 8; off >= 1; off >>= 1)
#pragma unroll
    for (int t = 0; t < 2; ++t)
#pragma unroll
      for (int r = 0; r < 4; ++r) {
        gmin[t][r][0] = fminf(gmin[t][r][0], __shfl_xor(gmin[t][r][0], off, 64));
        gmin[t][r][1] = fminf(gmin[t][r][1], __shfl_xor(gmin[t][r][1], off, 64));
      }

  __syncthreads();
  float* sred = (float*)Xs;
  if (ln == 0) {
#pragma unroll
    for (int t = 0; t < 2; ++t)
#pragma unroll
      for (int r = 0; r < 4; ++r) {
        int tl = wv * 32 + t * 16 + q * 4 + r;
        sred[tl * 2 + 0] = gmin[t][r][0];
        sred[tl * 2 + 1] = gmin[t][r][1];
      }
  }
  __syncthreads();
  if (tid < TM) {
    unsigned int pk = (unsigned int)f2h(sred[tid * 2])
                    | ((unsigned int)f2h(sred[tid * 2 + 1]) << 16);
    *(unsigned int*)(minima + (size_t)(tb * TM + tid) * NCHUNK + nb * 2) = pk;
  }
}

// ---------------- pass 2: LDS-staged exact rescue + epilogue -------------------------
// 128 threads = 2 waves; wave = token. Per flagged chunk: coalesced stage of the
// chunk's 64x64 f32 rows into padded LDS (stride 68 floats), then lane=code exact
// eval with the BYTE-IDENTICAL R1 arithmetic reading from LDS.
__global__ __launch_bounds__(128) void vq_rescue(
    const float* __restrict__ x, const float* __restrict__ cb,
    const float* __restrict__ sc, const unsigned short* __restrict__ minima,
    float* __restrict__ out_xq, float* __restrict__ out_idx,
    float* __restrict__ partial,
    const int* __restrict__ p_start, const int* __restrict__ p_end) {
#pragma clang fp contract(off)
  __shared__ float chunkbuf[2][CSZ * RSTRIDE];   // 2 x 17408 B
  __shared__ float xs[2][64];
  __shared__ float sdata[2];
  int tid  = threadIdx.x;
  int wv   = tid >> 6;
  int lane = tid & 63;
  int token = blockIdx.x * 2 + wv;

  float xx = x[(size_t)token * EDIM + lane];
  xs[wv][lane] = xx;
  __syncthreads();
  const float4* xl4 = (const float4*)xs[wv];     // broadcast reads: conflict-free

  // sx = np.sum(x*x) pairwise-8 replica
  float a[8];
#pragma unroll
  for (int j = 0; j < 8; ++j) a[j] = 0.0f;
#pragma unroll
  for (int i = 0; i < 8; ++i) {
    float4 pA = xl4[2*i], pB = xl4[2*i+1];
    a[0] += pA.x * pA.x; a[1] += pA.y * pA.y; a[2] += pA.z * pA.z; a[3] += pA.w * pA.w;
    a[4] += pB.x * pB.x; a[5] += pB.y * pB.y; a[6] += pB.z * pB.z; a[7] += pB.w * pB.w;
  }
  float sx = ((a[0]+a[1]) + (a[2]+a[3])) + ((a[4]+a[5]) + (a[6]+a[7]));

  // minima row: lane covers chunks {2*lane, 2*lane+1}
  unsigned int u = *(const unsigned int*)(minima + (size_t)token * NCHUNK + lane * 2);
  float mv0 = h2f((unsigned short)(u & 0xFFFFu));
  float mv1 = h2f((unsigned short)(u >> 16));
  float m = fminf(mv0, mv1);
#pragma unroll
  for (int off = 32; off >= 1; off >>= 1) m = fminf(m, __shfl_xor(m, off, 64));
  float thr = m + WINDOW;
  unsigned long long f0 = __ballot(mv0 <= thr);
  unsigned long long f1 = __ballot(mv1 <= thr);

  int s = *p_start, e = *p_end;
  unsigned long long bestpack = ~0ull;
  float* buf = chunkbuf[wv];

#pragma unroll 1
  for (int half = 0; half < 2; ++half) {
    unsigned long long fm = half ? f1 : f0;
    while (fm) {
      int c = __ffsll((long long)fm) - 1;
      fm &= fm - 1;
      int kb = (2 * c + half) * CSZ;
      // ---- stage chunk rows kb..kb+63 (16KB) cooperatively, coalesced ----
      const float4* src = (const float4*)(cb + (size_t)kb * EDIM);
#pragma unroll
      for (int p = 0; p < 16; ++p) {
        int idx = p * 64 + lane;                 // float4 index in chunk [0,1024)
        int row = idx >> 4, col = idx & 15;
        float4 v = src[idx];
        *(float4*)&buf[row * RSTRIDE + col * 4] = v;
      }
      asm volatile("s_waitcnt lgkmcnt(0)" ::: "memory");  // wave-level: writes visible
      // ---- exact eval: lane = code (byte-identical R1 arithmetic) ----
      int k = kb + lane;
      if (k >= s && k < e) {
        const float4* c4 = (const float4*)&buf[lane * RSTRIDE];
        float t[8];
#pragma unroll
        for (int j = 0; j < 8; ++j) t[j] = 0.0f;
#pragma unroll
        for (int i = 0; i < 8; ++i) {            // elements 8i..8i+7, i ascending
          float4 cA = c4[2*i], cB = c4[2*i+1];
          float4 pA = xl4[2*i], pB = xl4[2*i+1];
          t[0] += cA.x * pA.x; t[1] += cA.y * pA.y;
          t[2] += cA.z * pA.z; t[3] += cA.w * pA.w;
          t[4] += cB.x * pB.x; t[5] += cB.y * pB.y;
          t[6] += cB.z * pB.z; t[7] += cB.w * pB.w;
        }
        float tt = ((t[0]+t[1]) + (t[2]+t[3])) + ((t[4]+t[5]) + (t[6]+t[7]));
        float d = (sx + sc[k]) - 2.0f * tt;
        unsigned int db = __float_as_uint(d);
        unsigned int en = db ^ ((unsigned int)((int)db >> 31) | 0x80000000u);
        unsigned long long pk = ((unsigned long long)en << 32) | (unsigned int)k;
        if (pk < bestpack) bestpack = pk;
      }
      asm volatile("s_waitcnt lgkmcnt(0)" ::: "memory");  // reads done before restage
    }
  }
#pragma unroll
  for (int off = 32; off >= 1; off >>= 1) {
    unsigned long long o = __shfl_xor(bestpack, off, 64);
    if (o < bestpack) bestpack = o;
  }
  int bidx = (int)(unsigned int)(bestpack & 0xFFFFFFFFull);

  float qv = cb[(size_t)bidx * EDIM + lane];
  float diff = qv - xx;                              // fl(x_q - x)
  out_xq[(size_t)token * EDIM + lane] = xx + diff;   // fl(x + fl(x_q - x))
  if (lane == 0) out_idx[token] = (float)bidx;

  float l = diff * diff;
#pragma unroll
  for (int off = 32; off >= 1; off >>= 1) l += __shfl_down(l, off, 64);
  if (lane == 0) sdata[wv] = l;
  __syncthreads();
  if (tid == 0) partial[blockIdx.x] = sdata[0] + sdata[1];
}

// ---------------- final loss reduction ----------------------------------------------
__global__ __launch_bounds__(256) void vq_loss(const float* __restrict__ partial,
                                               float* __restrict__ out_loss) {
  int tid = threadIdx.x;
  float s = 0.0f;
  for (int i = tid; i < NTOK / 2; i += 256) s += partial[i];
#pragma unroll
  for (int off = 32; off >= 1; off >>= 1) s += __shfl_down(s, off, 64);
  __shared__ float sdata[4];
  if ((tid & 63) == 0) sdata[tid >> 6] = s;
  __syncthreads();
  if (tid == 0) {
    float total = (sdata[0] + sdata[1]) + (sdata[2] + sdata[3]);
    float m = total * (1.0f / (float)NELEM);
    out_loss[0] = m + 0.25f * m;
  }
}

// ---------------- launch -------------------------------------------------------------
extern "C" void kernel_launch(void* const* d_in, const int* in_sizes, int n_in,
                              void* d_out, int out_size, void* d_ws, size_t ws_size,
                              hipStream_t stream) {
  const float* x  = (const float*)d_in[0];
  const float* cb = (const float*)d_in[1];
  const int* p_start = (const int*)d_in[2];
  const int* p_end   = (const int*)d_in[3];

  float* ws = (float*)d_ws;
  float* sc      = ws;                                    // 8192 f
  float* partial = ws + N_E;                              // 16384 f
  unsigned short* xbf    = (unsigned short*)(ws + N_E + NTOK / 2);  // 2097152 us
  unsigned short* cbf    = xbf + (size_t)NTOK * EDIM;               // 524288 us
  unsigned short* minima = cbf + (size_t)N_E * EDIM;                // 32768*128 us

  float* out      = (float*)d_out;
  float* out_xq   = out;                 // 2097152
  float* out_loss = out + NELEM;         // 1
  float* out_idx  = out + NELEM + 1;     // 32768

  vq_prep<<<NELEM / 1024, 256, 0, stream>>>(x, xbf);
  vq_sc<<<N_E / 256, 256, 0, stream>>>(cb, sc, cbf);
  dim3 g1(NTOK / TM, N_E / TN);
  vq_pass1<<<g1, 256, 0, stream>>>(xbf, cbf, sc, minima, p_start, p_end);
  vq_rescue<<<NTOK / 2, 128, 0, stream>>>(x, cb, sc, minima, out_xq, out_idx,
                                          partial, p_start, p_end);
  vq_loss<<<1, 256, 0, stream>>>(partial, out_loss);
}

// Round 7
// 278.781 us; speedup vs baseline: 25.2079x; 1.0462x over previous
//
#include <hip/hip_runtime.h>
#include <math.h>

// VectorQuantizer: x (32768,64) f32, codebook (8192,64) f32, start/end/use_sk ints.
// Outputs concat: x_q_st (2097152 f32) | loss (1 f32) | indices (32768 as f32 values).
//
// R7 architecture: bf16-MFMA filter (swapped operands, sc folded into K) + exact rescue.
//  vq_prep: x -> xbf_ext rows [x0..x63, -0.5, 0*31] bf16 (K padded 64->96).
//  vq_sc:   sc_k exact (pairwise-8 numpy replica, f32) + cb -> cbf_ext rows
//           [c0..c63, bf16(sc_k), 0*31]. Then MFMA acc = dot - sc/2 exactly, so
//           per-chunk min g = -2 * max acc (sc->bf16 error <= 2e-9, negligible).
//  vq_pass1: A=cb rows (codes), B=x cols (tokens): D rows=codes -> chunk min is an
//           in-register fmax fold + 2 cross-q shuffles. Block = 64 tokens, loops all
//           64 code tiles with dbuf LDS; x staged once; one barrier/iter.
//           minima[token][chunk] f16, CSZ=32 (256 chunks).
//  vq_rescue: wave/token. Coalesced minima row, butterfly min -> thr, 4 ballots ->
//           flagged chunks; chunks processed in PAIRS (lanes 0-31 chunk A, 32-63
//           chunk B) from one staged LDS buffer; eval uses the BIT-EXACT R1
//           numpy-replica arithmetic (pairwise-8, separate mul+add); lex-min on
//           packed (enc(d), k) == strict-< ascending-k first-occurrence.
// Filter-error budget (W=3e-4, validated R5/R6): 2*bf16 dot err (<=8e-5 worst each)
// + f16 store (<=8e-6 each) + reference d-slop (1.5e-5) ~= 1.9e-4 < 3e-4.
// DO NOT change the exact-path arithmetic: inter-code d gaps are ~1 ulp of d.

#define N_E    8192
#define EDIM   64
#define NTOK   32768
#define NELEM  (NTOK * EDIM)
#define CSZ    32                  // chunk size
#define NCHUNK (N_E / CSZ)         // 256 chunks
#define WINDOW 3e-4f
#define KEXT   96                  // padded K (64 data + sc-fold + zeros)
#define LROW   104                 // pass-1 LDS row stride (ushorts; 13*8, 16B-mult)
#define RSTRIDE 68                 // rescue LDS row stride (floats, 272B)

typedef __attribute__((ext_vector_type(8))) short          short8;
typedef __attribute__((ext_vector_type(8))) unsigned short ushort8v;
typedef __attribute__((ext_vector_type(4))) unsigned short ushort4v;
typedef __attribute__((ext_vector_type(4))) float          f32x4;

__device__ __forceinline__ unsigned short f2bf(float f) {   // RTNE f32->bf16 bits
  unsigned int u = __float_as_uint(f);
  return (unsigned short)((u + 0x7FFFu + ((u >> 16) & 1u)) >> 16);
}
__device__ __forceinline__ unsigned short f2h(float f) {
  union { _Float16 h; unsigned short u; } cv; cv.h = (_Float16)f; return cv.u;
}
__device__ __forceinline__ float h2f(unsigned short b) {
  union { _Float16 h; unsigned short u; } cv; cv.u = b; return (float)cv.h;
}

// ---------------- prep: x -> bf16 ext rows [x, -0.5, zeros] --------------------------
__global__ __launch_bounds__(256) void vq_prep(const float* __restrict__ x,
                                               unsigned short* __restrict__ xbf) {
  int tid = threadIdx.x;
  int r0 = blockIdx.x * 32;                       // 32 rows per block
  const float4* xg = (const float4*)(x + (size_t)r0 * EDIM);
#pragma unroll
  for (int p = 0; p < 2; ++p) {
    int idx = tid + p * 256;                      // [0,512): row*16 + c4
    int row = idx >> 4, c4 = idx & 15;
    float4 f = xg[idx];
    ushort4v o = {f2bf(f.x), f2bf(f.y), f2bf(f.z), f2bf(f.w)};
    *(ushort4v*)&xbf[(size_t)(r0 + row) * KEXT + c4 * 4] = o;
  }
  if (tid < 128) {                                // tail cols 64..95
    int row = tid >> 2, seg = tid & 3;
    ushort8v v = {0,0,0,0,0,0,0,0};
    if (seg == 0) v[0] = f2bf(-0.5f);
    *(ushort8v*)&xbf[(size_t)(r0 + row) * KEXT + 64 + seg * 8] = v;
  }
}

// ---------------- sc (exact pairwise-8) + cb -> bf16 ext rows [c, sc, zeros] ---------
__global__ __launch_bounds__(256) void vq_sc(const float* __restrict__ cb,
                                             float* __restrict__ sc,
                                             unsigned short* __restrict__ cbf) {
#pragma clang fp contract(off)
  int r = blockIdx.x * 256 + threadIdx.x;
  const float4* c4 = (const float4*)(cb + (size_t)r * EDIM);
  float a[8];
#pragma unroll
  for (int j = 0; j < 8; ++j) a[j] = 0.0f;
#pragma unroll
  for (int i = 0; i < 8; ++i) {
    float4 pA = c4[2*i], pB = c4[2*i+1];
    a[0] += pA.x * pA.x; a[1] += pA.y * pA.y; a[2] += pA.z * pA.z; a[3] += pA.w * pA.w;
    a[4] += pB.x * pB.x; a[5] += pB.y * pB.y; a[6] += pB.z * pB.z; a[7] += pB.w * pB.w;
  }
  float sval = ((a[0]+a[1]) + (a[2]+a[3])) + ((a[4]+a[5]) + (a[6]+a[7]));
  sc[r] = sval;
  unsigned short* dst = cbf + (size_t)r * KEXT;
#pragma unroll
  for (int h = 0; h < 8; ++h) {                   // 8 ushort8 of data
    float4 fA = c4[2*h], fB = c4[2*h+1];
    ushort8v o = {f2bf(fA.x), f2bf(fA.y), f2bf(fA.z), f2bf(fA.w),
                  f2bf(fB.x), f2bf(fB.y), f2bf(fB.z), f2bf(fB.w)};
    *(ushort8v*)&dst[h * 8] = o;
  }
  ushort8v t0 = {0,0,0,0,0,0,0,0};
  t0[0] = f2bf(sval);
  *(ushort8v*)&dst[64] = t0;
  ushort8v z = {0,0,0,0,0,0,0,0};
  *(ushort8v*)&dst[72] = z;
  *(ushort8v*)&dst[80] = z;
  *(ushort8v*)&dst[88] = z;
}

// ---------------- pass 1: swapped-operand MFMA filter, nb-loop, dbuf -----------------
// Block = 64 tokens (4 waves x 16), loops 64 code tiles of 128. A=cb, B=x:
// D[row=code=q*4+r (+16ct)][col=token=ln]. acc = dot - sc/2 (K-fold); min g = -2 max.
__global__ __launch_bounds__(256) void vq_pass1(
    const unsigned short* __restrict__ xbf, const unsigned short* __restrict__ cbf,
    unsigned short* __restrict__ minima,
    const int* __restrict__ p_start, const int* __restrict__ p_end) {
  __shared__ unsigned short Xs[64 * LROW];        // 13312 B
  __shared__ unsigned short Cs[2][128 * LROW];    // 2 x 26624 B
  int tid = threadIdx.x;
  int tb = blockIdx.x;                            // 512 token blocks
  int s = *p_start, e = *p_end;

  // stage x tile once: 64 rows x 12 ushort8 = 768
  const ushort8v* xg = (const ushort8v*)(xbf + (size_t)tb * 64 * KEXT);
#pragma unroll
  for (int p = 0; p < 3; ++p) {
    int idx = tid + p * 256;
    int row = idx / 12, h = idx % 12;
    *(ushort8v*)&Xs[row * LROW + h * 8] = xg[idx];
  }
  // stage code tile 0: 128 rows x 12 ushort8 = 1536
  const ushort8v* cg0 = (const ushort8v*)cbf;
#pragma unroll
  for (int p = 0; p < 6; ++p) {
    int idx = tid + p * 256;
    int row = idx / 12, h = idx % 12;
    *(ushort8v*)&Cs[0][row * LROW + h * 8] = cg0[idx];
  }
  __syncthreads();

  int lane = tid & 63, wv = tid >> 6;
  int q = lane >> 4, ln = lane & 15;
  // B-frags (x, token = wv*16+ln): iter-invariant, hoisted
  const unsigned short* xrow = &Xs[(wv * 16 + ln) * LROW];
  short8 bfr[3];
#pragma unroll
  for (int ks = 0; ks < 3; ++ks) bfr[ks] = *(const short8*)&xrow[ks * 32 + q * 8];

  int token = tb * 64 + wv * 16 + ln;
  f32x4 zero = {0.0f, 0.0f, 0.0f, 0.0f};

  for (int nb = 0; nb < 64; ++nb) {
    int cur = nb & 1;
    // prefetch next tile into regs
    ushort8v creg[6];
    if (nb < 63) {
      const ushort8v* cg = (const ushort8v*)(cbf + (size_t)(nb + 1) * 128 * KEXT);
#pragma unroll
      for (int p = 0; p < 6; ++p) creg[p] = cg[tid + p * 256];
    }
    // compute: 8 code tiles x 3 ks
    f32x4 acc[8];
#pragma unroll
    for (int ct = 0; ct < 8; ++ct) {
      const unsigned short* crow = &Cs[cur][(ct * 16 + ln) * LROW];
      short8 a0 = *(const short8*)&crow[0 * 32 + q * 8];
      short8 a1 = *(const short8*)&crow[1 * 32 + q * 8];
      short8 a2 = *(const short8*)&crow[2 * 32 + q * 8];
      f32x4 ac = __builtin_amdgcn_mfma_f32_16x16x32_bf16(a0, bfr[0], zero, 0, 0, 0);
      ac = __builtin_amdgcn_mfma_f32_16x16x32_bf16(a1, bfr[1], ac, 0, 0, 0);
      ac = __builtin_amdgcn_mfma_f32_16x16x32_bf16(a2, bfr[2], ac, 0, 0, 0);
      acc[ct] = ac;
    }
    // epilogue: per 32-code chunk, max acc in-register + 2 cross-q shuffles
    int cbase = nb * 128;
    bool full = (cbase >= s) && (cbase + 128 <= e);
    float mcp[4];
#pragma unroll
    for (int cp = 0; cp < 4; ++cp) {
      float v = -INFINITY;
#pragma unroll
      for (int h = 0; h < 2; ++h) {
        int ct = 2 * cp + h;
        if (full) {
          v = fmaxf(v, fmaxf(fmaxf(acc[ct][0], acc[ct][1]),
                             fmaxf(acc[ct][2], acc[ct][3])));
        } else {
#pragma unroll
          for (int r = 0; r < 4; ++r) {
            int code = cbase + ct * 16 + q * 4 + r;
            if (code >= s && code < e) v = fmaxf(v, acc[ct][r]);
          }
        }
      }
      v = fmaxf(v, __shfl_xor(v, 16, 64));
      v = fmaxf(v, __shfl_xor(v, 32, 64));
      mcp[cp] = v;
    }
    if (q == 0) {                                  // 16 lanes write this wave's tokens
      unsigned int lo = (unsigned int)f2h(-2.0f * mcp[0])
                      | ((unsigned int)f2h(-2.0f * mcp[1]) << 16);
      unsigned int hi = (unsigned int)f2h(-2.0f * mcp[2])
                      | ((unsigned int)f2h(-2.0f * mcp[3]) << 16);
      uint2 pk; pk.x = lo; pk.y = hi;
      *(uint2*)(minima + (size_t)token * NCHUNK + nb * 4) = pk;
    }
    // write next tile to the other buffer
    if (nb < 63) {
#pragma unroll
      for (int p = 0; p < 6; ++p) {
        int idx = tid + p * 256;
        int row = idx / 12, h = idx % 12;
        *(ushort8v*)&Cs[1 - cur][row * LROW + h * 8] = creg[p];
      }
    }
    __syncthreads();
  }
}

// ---------------- pass 2: paired-chunk LDS-staged exact rescue + epilogue ------------
__global__ __launch_bounds__(128) void vq_rescue(
    const float* __restrict__ x, const float* __restrict__ cb,
    const float* __restrict__ sc, const unsigned short* __restrict__ minima,
    float* __restrict__ out_xq, float* __restrict__ out_idx,
    float* __restrict__ partial,
    const int* __restrict__ p_start, const int* __restrict__ p_end) {
#pragma clang fp contract(off)
  __shared__ float chunkbuf[2][2 * CSZ * RSTRIDE];  // 2 waves x 17408 B (64 rows)
  __shared__ float xs[2][64];
  __shared__ float sdata[2];
  int tid  = threadIdx.x;
  int wv   = tid >> 6;
  int lane = tid & 63;
  int token = blockIdx.x * 2 + wv;

  float xx = x[(size_t)token * EDIM + lane];
  xs[wv][lane] = xx;
  __syncthreads();
  const float4* xl4 = (const float4*)xs[wv];

  // sx = np.sum(x*x) pairwise-8 replica
  float a[8];
#pragma unroll
  for (int j = 0; j < 8; ++j) a[j] = 0.0f;
#pragma unroll
  for (int i = 0; i < 8; ++i) {
    float4 pA = xl4[2*i], pB = xl4[2*i+1];
    a[0] += pA.x * pA.x; a[1] += pA.y * pA.y; a[2] += pA.z * pA.z; a[3] += pA.w * pA.w;
    a[4] += pB.x * pB.x; a[5] += pB.y * pB.y; a[6] += pB.z * pB.z; a[7] += pB.w * pB.w;
  }
  float sx = ((a[0]+a[1]) + (a[2]+a[3])) + ((a[4]+a[5]) + (a[6]+a[7]));

  // minima row: lane covers chunks 4*lane .. 4*lane+3 (coalesced uint2)
  uint2 u2 = *(const uint2*)(minima + (size_t)token * NCHUNK + lane * 4);
  float mv[4] = {h2f((unsigned short)(u2.x & 0xFFFFu)),
                 h2f((unsigned short)(u2.x >> 16)),
                 h2f((unsigned short)(u2.y & 0xFFFFu)),
                 h2f((unsigned short)(u2.y >> 16))};
  float m = fminf(fminf(mv[0], mv[1]), fminf(mv[2], mv[3]));
#pragma unroll
  for (int off = 32; off >= 1; off >>= 1) m = fminf(m, __shfl_xor(m, off, 64));
  float thr = m + WINDOW;
  unsigned long long fmask[4];
#pragma unroll
  for (int cc = 0; cc < 4; ++cc) fmask[cc] = __ballot(mv[cc] <= thr);

  int s = *p_start, e = *p_end;
  unsigned long long bestpack = ~0ull;
  float* buf = chunkbuf[wv];
  int pend = -1;

#pragma unroll 1
  for (int cc = 0; cc < 5; ++cc) {                // cc==4: flush pending
    unsigned long long fm = (cc < 4) ? fmask[cc] : 0ull;
    while (fm || (cc == 4 && pend >= 0)) {
      int cA, cB;
      if (cc == 4) { cA = pend; cB = -1; pend = -2; }
      else {
        int b = __ffsll((long long)fm) - 1; fm &= fm - 1;
        int c = 4 * b + cc;
        if (pend < 0) { pend = c; continue; }
        cA = pend; cB = c; pend = -1;
      }
      // ---- stage chunk(s): cA -> rows 0..31, cB -> rows 32..63, coalesced ----
      {
        const float4* srcA = (const float4*)(cb + (size_t)cA * CSZ * EDIM);
#pragma unroll
        for (int p = 0; p < 8; ++p) {
          int idx = p * 64 + lane;                // [0,512): row*16+col
          int row = idx >> 4, col = idx & 15;
          *(float4*)&buf[row * RSTRIDE + col * 4] = srcA[idx];
        }
        if (cB >= 0) {
          const float4* srcB = (const float4*)(cb + (size_t)cB * CSZ * EDIM);
#pragma unroll
          for (int p = 0; p < 8; ++p) {
            int idx = p * 64 + lane;
            int row = idx >> 4, col = idx & 15;
            *(float4*)&buf[(CSZ + row) * RSTRIDE + col * 4] = srcB[idx];
          }
        }
      }
      asm volatile("s_waitcnt lgkmcnt(0)" ::: "memory");
      // ---- exact eval: half-wave per chunk (byte-identical R1 arithmetic) ----
      int half = lane >> 5;
      int ch = half ? cB : cA;
      int k = ch * CSZ + (lane & 31);
      if (ch >= 0 && k >= s && k < e) {
        const float4* c4 = (const float4*)&buf[(half * CSZ + (lane & 31)) * RSTRIDE];
        float t[8];
#pragma unroll
        for (int j = 0; j < 8; ++j) t[j] = 0.0f;
#pragma unroll
        for (int i = 0; i < 8; ++i) {             // elements 8i..8i+7, i ascending
          float4 cA4 = c4[2*i], cB4 = c4[2*i+1];
          float4 pA = xl4[2*i], pB = xl4[2*i+1];
          t[0] += cA4.x * pA.x; t[1] += cA4.y * pA.y;
          t[2] += cA4.z * pA.z; t[3] += cA4.w * pA.w;
          t[4] += cB4.x * pB.x; t[5] += cB4.y * pB.y;
          t[6] += cB4.z * pB.z; t[7] += cB4.w * pB.w;
        }
        float tt = ((t[0]+t[1]) + (t[2]+t[3])) + ((t[4]+t[5]) + (t[6]+t[7]));
        float d = (sx + sc[k]) - 2.0f * tt;
        unsigned int db = __float_as_uint(d);
        unsigned int en = db ^ ((unsigned int)((int)db >> 31) | 0x80000000u);
        unsigned long long pk = ((unsigned long long)en << 32) | (unsigned int)k;
        if (pk < bestpack) bestpack = pk;
      }
      asm volatile("s_waitcnt lgkmcnt(0)" ::: "memory");
      if (pend == -2) { pend = -1; break; }
    }
  }
  // lex-min reduce: (d asc, k asc) == numpy first-occurrence argmin
#pragma unroll
  for (int off = 32; off >= 1; off >>= 1) {
    unsigned long long o = __shfl_xor(bestpack, off, 64);
    if (o < bestpack) bestpack = o;
  }
  int bidx = (int)(unsigned int)(bestpack & 0xFFFFFFFFull);

  float qv = cb[(size_t)bidx * EDIM + lane];
  float diff = qv - xx;                              // fl(x_q - x)
  out_xq[(size_t)token * EDIM + lane] = xx + diff;   // fl(x + fl(x_q - x))
  if (lane == 0) out_idx[token] = (float)bidx;

  float l = diff * diff;
#pragma unroll
  for (int off = 32; off >= 1; off >>= 1) l += __shfl_down(l, off, 64);
  if (lane == 0) sdata[wv] = l;
  __syncthreads();
  if (tid == 0) partial[blockIdx.x] = sdata[0] + sdata[1];
}

// ---------------- final loss reduction ----------------------------------------------
__global__ __launch_bounds__(256) void vq_loss(const float* __restrict__ partial,
                                               float* __restrict__ out_loss) {
  int tid = threadIdx.x;
  float s = 0.0f;
  for (int i = tid; i < NTOK / 2; i += 256) s += partial[i];
#pragma unroll
  for (int off = 32; off >= 1; off >>= 1) s += __shfl_down(s, off, 64);
  __shared__ float sdata[4];
  if ((tid & 63) == 0) sdata[tid >> 6] = s;
  __syncthreads();
  if (tid == 0) {
    float total = (sdata[0] + sdata[1]) + (sdata[2] + sdata[3]);
    float m = total * (1.0f / (float)NELEM);
    out_loss[0] = m + 0.25f * m;
  }
}

// ---------------- launch -------------------------------------------------------------
extern "C" void kernel_launch(void* const* d_in, const int* in_sizes, int n_in,
                              void* d_out, int out_size, void* d_ws, size_t ws_size,
                              hipStream_t stream) {
  const float* x  = (const float*)d_in[0];
  const float* cb = (const float*)d_in[1];
  const int* p_start = (const int*)d_in[2];
  const int* p_end   = (const int*)d_in[3];

  float* ws = (float*)d_ws;
  float* sc      = ws;                                            // 8192 f
  float* partial = ws + N_E;                                      // 16384 f
  unsigned short* xbf    = (unsigned short*)(ws + N_E + NTOK/2);  // 32768*96 us (6MB)
  unsigned short* cbf    = xbf + (size_t)NTOK * KEXT;             // 8192*96 us (1.5MB)
  unsigned short* minima = cbf + (size_t)N_E * KEXT;              // 32768*256 us (16MB)

  float* out      = (float*)d_out;
  float* out_xq   = out;                 // 2097152
  float* out_loss = out + NELEM;         // 1
  float* out_idx  = out + NELEM + 1;     // 32768

  vq_prep<<<NTOK / 32, 256, 0, stream>>>(x, xbf);
  vq_sc<<<N_E / 256, 256, 0, stream>>>(cb, sc, cbf);
  vq_pass1<<<NTOK / 64, 256, 0, stream>>>(xbf, cbf, minima, p_start, p_end);
  vq_rescue<<<NTOK / 2, 128, 0, stream>>>(x, cb, sc, minima, out_xq, out_idx,
                                          partial, p_start, p_end);
  vq_loss<<<1, 256, 0, stream>>>(partial, out_loss);
}

// Round 8
// 228.932 us; speedup vs baseline: 30.6969x; 1.2177x over previous
//
#include <hip/hip_runtime.h>
#include <math.h>

// VectorQuantizer: x (32768,64) f32, codebook (8192,64) f32, start/end/use_sk ints.
// Outputs concat: x_q_st (2097152 f32) | loss (1 f32) | indices (32768 as f32 values).
//
// R8: bf16-MFMA filter, LDS-amortized (32x32x16 + 2-token-group register blocking),
// prep fused into pass1. Exact rescue unchanged (validated R6/R7, absmax 0.0).
//  vq_sc:   sc_k exact (pairwise-8 numpy replica, f32) + cb -> cbf_ext rows
//           [c0..c63, bf16(sc_k), 0*31] (K padded 64->96).
//  vq_pass1: block = 256 tokens x 2048 codes (16 iters of 128). A=cb rows (codes),
//           B=x cols (tokens): acc = dot - sc/2 (sc folded into K via x-ext [-0.5]).
//           Wave: 64 tokens (2 B-groups, hoisted) x 128 codes (4 ct) x 6 ks = 48 MFMA
//           per iter, 24 A-reads -> 2 MFMA per ds_read_b128 + 2x FLOP/read vs 16x16.
//           LDS stride 104 ushorts (52 dwords == 4 mod 8): uniform 8-access/bank on
//           all b128 reads (conflict-free floor). Chunk(32)-min = in-reg fmax fold +
//           xor-32 shuffle; minima[token][chunk] f16.
//  vq_rescue: wave/token, paired-chunk LDS staging, BIT-EXACT R1 numpy-replica eval
//           (pairwise-8, separate mul+add); lex-min (enc(d),k) == strict-< ascending-k.
// Filter-error budget (W=3e-4, validated): bf16 dot err + f16 store + ref d-slop
// ~= 1.9e-4 < 3e-4. DO NOT change the exact-path arithmetic.

#define N_E    8192
#define EDIM   64
#define NTOK   32768
#define NELEM  (NTOK * EDIM)
#define CSZ    32                  // chunk size
#define NCHUNK (N_E / CSZ)         // 256 chunks
#define WINDOW 3e-4f
#define KEXT   96                  // padded K (64 data + sc-fold + zeros)
#define TTOK   256                 // pass-1 tokens per block
#define TCODE  2048                // pass-1 codes per block (16 iters of 128)
#define SROW   104                 // LDS row stride (ushorts; 52 dwords == 4 mod 8)
#define RSTRIDE 68                 // rescue LDS row stride (floats, 272B)

typedef __attribute__((ext_vector_type(8)))  short          short8;
typedef __attribute__((ext_vector_type(8)))  unsigned short ushort8v;
typedef __attribute__((ext_vector_type(4)))  unsigned short ushort4v;
typedef __attribute__((ext_vector_type(16))) float          f32x16;

__device__ __forceinline__ unsigned short f2bf(float f) {   // RTNE f32->bf16 bits
  unsigned int u = __float_as_uint(f);
  return (unsigned short)((u + 0x7FFFu + ((u >> 16) & 1u)) >> 16);
}
__device__ __forceinline__ unsigned short f2h(float f) {
  union { _Float16 h; unsigned short u; } cv; cv.h = (_Float16)f; return cv.u;
}
__device__ __forceinline__ float h2f(unsigned short b) {
  union { _Float16 h; unsigned short u; } cv; cv.u = b; return (float)cv.h;
}

// ---------------- sc (exact pairwise-8) + cb -> bf16 ext rows [c, sc, zeros] ---------
__global__ __launch_bounds__(256) void vq_sc(const float* __restrict__ cb,
                                             float* __restrict__ sc,
                                             unsigned short* __restrict__ cbf) {
#pragma clang fp contract(off)
  int r = blockIdx.x * 256 + threadIdx.x;
  const float4* c4 = (const float4*)(cb + (size_t)r * EDIM);
  float a[8];
#pragma unroll
  for (int j = 0; j < 8; ++j) a[j] = 0.0f;
#pragma unroll
  for (int i = 0; i < 8; ++i) {
    float4 pA = c4[2*i], pB = c4[2*i+1];
    a[0] += pA.x * pA.x; a[1] += pA.y * pA.y; a[2] += pA.z * pA.z; a[3] += pA.w * pA.w;
    a[4] += pB.x * pB.x; a[5] += pB.y * pB.y; a[6] += pB.z * pB.z; a[7] += pB.w * pB.w;
  }
  float sval = ((a[0]+a[1]) + (a[2]+a[3])) + ((a[4]+a[5]) + (a[6]+a[7]));
  sc[r] = sval;
  unsigned short* dst = cbf + (size_t)r * KEXT;
#pragma unroll
  for (int h = 0; h < 8; ++h) {
    float4 fA = c4[2*h], fB = c4[2*h+1];
    ushort8v o = {f2bf(fA.x), f2bf(fA.y), f2bf(fA.z), f2bf(fA.w),
                  f2bf(fB.x), f2bf(fB.y), f2bf(fB.z), f2bf(fB.w)};
    *(ushort8v*)&dst[h * 8] = o;
  }
  ushort8v t0 = {0,0,0,0,0,0,0,0};
  t0[0] = f2bf(sval);
  *(ushort8v*)&dst[64] = t0;
  ushort8v z = {0,0,0,0,0,0,0,0};
  *(ushort8v*)&dst[72] = z;
  *(ushort8v*)&dst[80] = z;
  *(ushort8v*)&dst[88] = z;
}

// ---------------- pass 1: 32x32x16 MFMA filter, token-register-blocked ---------------
// Frags: A[m=lane&31][k=8*(lane>>5)+j] (codes), B[n=lane&31][k same] (tokens),
// D: col=lane&31 (token), row=(reg&3)+8*(reg>>2)+4*(lane>>5) (code).
__global__ __launch_bounds__(256, 2) void vq_pass1(
    const float* __restrict__ x, const unsigned short* __restrict__ cbf,
    unsigned short* __restrict__ minima,
    const int* __restrict__ p_start, const int* __restrict__ p_end) {
  __shared__ unsigned short Xs[TTOK * SROW];   // 53248 B
  __shared__ unsigned short Cs[128 * SROW];    // 26624 B
  int tid = threadIdx.x;
  int tb = blockIdx.x;    // token split [0,128)
  int cbk = blockIdx.y;   // code split  [0,4)
  int s = *p_start, e = *p_end;

  // ---- stage x tile (fused f32 -> bf16-ext conversion) ----
  const float4* xg = (const float4*)(x + (size_t)tb * TTOK * EDIM);
#pragma unroll
  for (int p = 0; p < 16; ++p) {
    int idx = tid + p * 256;                   // [0,4096): row*16 + c4
    int row = idx >> 4, c4i = idx & 15;
    float4 f = xg[idx];
    ushort4v o = {f2bf(f.x), f2bf(f.y), f2bf(f.z), f2bf(f.w)};
    *(ushort4v*)&Xs[row * SROW + c4i * 4] = o;
  }
  {                                            // tail cols 64..95: [-0.5, zeros]
    ushort8v t0 = {0,0,0,0,0,0,0,0};
    t0[0] = f2bf(-0.5f);
    ushort8v z = {0,0,0,0,0,0,0,0};
    *(ushort8v*)&Xs[tid * SROW + 64] = t0;
    *(ushort8v*)&Xs[tid * SROW + 72] = z;
    *(ushort8v*)&Xs[tid * SROW + 80] = z;
    *(ushort8v*)&Xs[tid * SROW + 88] = z;
  }
  // ---- stage first code tile ----
  const ushort8v* cg0 = (const ushort8v*)(cbf + (size_t)cbk * TCODE * KEXT);
#pragma unroll
  for (int p = 0; p < 6; ++p) {
    int idx = tid + p * 256;                   // [0,1536)
    int row = idx / 12, h = idx % 12;
    *(ushort8v*)&Cs[row * SROW + h * 8] = cg0[idx];
  }
  __syncthreads();

  int lane = tid & 63, wv = tid >> 6;
  int half = lane >> 5, ln = lane & 31;
  int tokbase = wv * 64;                       // wave: tokens tokbase..+63 (2 groups)
  // hoisted B-frags (x is loop-invariant): 2 tg x 6 ks
  short8 bfr[2][6];
#pragma unroll
  for (int tg = 0; tg < 2; ++tg)
#pragma unroll
    for (int ks = 0; ks < 6; ++ks)
      bfr[tg][ks] = *(const short8*)&Xs[(tokbase + tg*32 + ln) * SROW + ks*16 + half*8];

  for (int nb = 0; nb < 16; ++nb) {
    // prefetch next code tile into regs
    ushort8v creg[6];
    if (nb < 15) {
      const ushort8v* cg =
          (const ushort8v*)(cbf + ((size_t)cbk * TCODE + (nb + 1) * 128) * KEXT);
#pragma unroll
      for (int p = 0; p < 6; ++p) creg[p] = cg[tid + p * 256];
    }
    // compute: 4 ct x 2 tg x 6 ks (each A-read feeds 2 MFMAs)
    f32x16 acc[2][4];
#pragma unroll
    for (int tg = 0; tg < 2; ++tg)
#pragma unroll
      for (int ct = 0; ct < 4; ++ct) acc[tg][ct] = (f32x16)0.0f;
#pragma unroll
    for (int ks = 0; ks < 6; ++ks)
#pragma unroll
      for (int ct = 0; ct < 4; ++ct) {
        short8 a = *(const short8*)&Cs[(ct*32 + ln) * SROW + ks*16 + half*8];
        acc[0][ct] = __builtin_amdgcn_mfma_f32_32x32x16_bf16(a, bfr[0][ks],
                                                             acc[0][ct], 0, 0, 0);
        acc[1][ct] = __builtin_amdgcn_mfma_f32_32x32x16_bf16(a, bfr[1][ks],
                                                             acc[1][ct], 0, 0, 0);
      }
    __syncthreads();                           // all Cs reads done
    if (nb < 15) {                             // write prefetched tile
#pragma unroll
      for (int p = 0; p < 6; ++p) {
        int idx = tid + p * 256;
        int row = idx / 12, h = idx % 12;
        *(ushort8v*)&Cs[row * SROW + h * 8] = creg[p];
      }
    }
    // epilogue (registers only; overlaps LDS writes): chunk = ct tile (32 codes)
    int cbase0 = cbk * TCODE + nb * 128;
    float vm[2][4];
#pragma unroll
    for (int ct = 0; ct < 4; ++ct) {
      int c0 = cbase0 + ct * 32;
      bool full = (c0 >= s) && (c0 + 32 <= e);
#pragma unroll
      for (int tg = 0; tg < 2; ++tg) {
        float v = -INFINITY;
        if (full) {
#pragma unroll
          for (int r = 0; r < 16; ++r) v = fmaxf(v, acc[tg][ct][r]);
        } else {
#pragma unroll
          for (int r = 0; r < 16; ++r) {
            int code = c0 + (r & 3) + 8 * (r >> 2) + 4 * half;
            if (code >= s && code < e) v = fmaxf(v, acc[tg][ct][r]);
          }
        }
        v = fmaxf(v, __shfl_xor(v, 32, 64));   // merge the two code-half groups
        vm[tg][ct] = v;
      }
    }
    // lane writes ITS token's 4 chunk-minima: token = tokbase + lane (tg = half)
    float m0 = half ? vm[1][0] : vm[0][0];
    float m1 = half ? vm[1][1] : vm[0][1];
    float m2 = half ? vm[1][2] : vm[0][2];
    float m3 = half ? vm[1][3] : vm[0][3];
    int token = tb * TTOK + tokbase + lane;
    uint2 pk;
    pk.x = (unsigned int)f2h(-2.0f * m0) | ((unsigned int)f2h(-2.0f * m1) << 16);
    pk.y = (unsigned int)f2h(-2.0f * m2) | ((unsigned int)f2h(-2.0f * m3) << 16);
    *(uint2*)(minima + (size_t)token * NCHUNK + (cbase0 >> 5)) = pk;
    __syncthreads();                           // Cs writes visible before next compute
  }
}

// ---------------- pass 2: paired-chunk LDS-staged exact rescue + epilogue ------------
__global__ __launch_bounds__(128) void vq_rescue(
    const float* __restrict__ x, const float* __restrict__ cb,
    const float* __restrict__ sc, const unsigned short* __restrict__ minima,
    float* __restrict__ out_xq, float* __restrict__ out_idx,
    float* __restrict__ partial,
    const int* __restrict__ p_start, const int* __restrict__ p_end) {
#pragma clang fp contract(off)
  __shared__ float chunkbuf[2][2 * CSZ * RSTRIDE];  // 2 waves x 17408 B (64 rows)
  __shared__ float xs[2][64];
  __shared__ float sdata[2];
  int tid  = threadIdx.x;
  int wv   = tid >> 6;
  int lane = tid & 63;
  int token = blockIdx.x * 2 + wv;

  float xx = x[(size_t)token * EDIM + lane];
  xs[wv][lane] = xx;
  __syncthreads();
  const float4* xl4 = (const float4*)xs[wv];

  // sx = np.sum(x*x) pairwise-8 replica
  float a[8];
#pragma unroll
  for (int j = 0; j < 8; ++j) a[j] = 0.0f;
#pragma unroll
  for (int i = 0; i < 8; ++i) {
    float4 pA = xl4[2*i], pB = xl4[2*i+1];
    a[0] += pA.x * pA.x; a[1] += pA.y * pA.y; a[2] += pA.z * pA.z; a[3] += pA.w * pA.w;
    a[4] += pB.x * pB.x; a[5] += pB.y * pB.y; a[6] += pB.z * pB.z; a[7] += pB.w * pB.w;
  }
  float sx = ((a[0]+a[1]) + (a[2]+a[3])) + ((a[4]+a[5]) + (a[6]+a[7]));

  // minima row: lane covers chunks 4*lane .. 4*lane+3 (coalesced uint2)
  uint2 u2 = *(const uint2*)(minima + (size_t)token * NCHUNK + lane * 4);
  float mv[4] = {h2f((unsigned short)(u2.x & 0xFFFFu)),
                 h2f((unsigned short)(u2.x >> 16)),
                 h2f((unsigned short)(u2.y & 0xFFFFu)),
                 h2f((unsigned short)(u2.y >> 16))};
  float m = fminf(fminf(mv[0], mv[1]), fminf(mv[2], mv[3]));
#pragma unroll
  for (int off = 32; off >= 1; off >>= 1) m = fminf(m, __shfl_xor(m, off, 64));
  float thr = m + WINDOW;
  unsigned long long fmask[4];
#pragma unroll
  for (int cc = 0; cc < 4; ++cc) fmask[cc] = __ballot(mv[cc] <= thr);

  int s = *p_start, e = *p_end;
  unsigned long long bestpack = ~0ull;
  float* buf = chunkbuf[wv];
  int pend = -1;

#pragma unroll 1
  for (int cc = 0; cc < 5; ++cc) {                // cc==4: flush pending
    unsigned long long fm = (cc < 4) ? fmask[cc] : 0ull;
    while (fm || (cc == 4 && pend >= 0)) {
      int cA, cB;
      if (cc == 4) { cA = pend; cB = -1; pend = -2; }
      else {
        int b = __ffsll((long long)fm) - 1; fm &= fm - 1;
        int c = 4 * b + cc;
        if (pend < 0) { pend = c; continue; }
        cA = pend; cB = c; pend = -1;
      }
      {
        const float4* srcA = (const float4*)(cb + (size_t)cA * CSZ * EDIM);
#pragma unroll
        for (int p = 0; p < 8; ++p) {
          int idx = p * 64 + lane;
          int row = idx >> 4, col = idx & 15;
          *(float4*)&buf[row * RSTRIDE + col * 4] = srcA[idx];
        }
        if (cB >= 0) {
          const float4* srcB = (const float4*)(cb + (size_t)cB * CSZ * EDIM);
#pragma unroll
          for (int p = 0; p < 8; ++p) {
            int idx = p * 64 + lane;
            int row = idx >> 4, col = idx & 15;
            *(float4*)&buf[(CSZ + row) * RSTRIDE + col * 4] = srcB[idx];
          }
        }
      }
      asm volatile("s_waitcnt lgkmcnt(0)" ::: "memory");
      int half = lane >> 5;
      int ch = half ? cB : cA;
      int k = ch * CSZ + (lane & 31);
      if (ch >= 0 && k >= s && k < e) {
        const float4* c4 = (const float4*)&buf[(half * CSZ + (lane & 31)) * RSTRIDE];
        float t[8];
#pragma unroll
        for (int j = 0; j < 8; ++j) t[j] = 0.0f;
#pragma unroll
        for (int i = 0; i < 8; ++i) {             // elements 8i..8i+7, i ascending
          float4 cA4 = c4[2*i], cB4 = c4[2*i+1];
          float4 pA = xl4[2*i], pB = xl4[2*i+1];
          t[0] += cA4.x * pA.x; t[1] += cA4.y * pA.y;
          t[2] += cA4.z * pA.z; t[3] += cA4.w * pA.w;
          t[4] += cB4.x * pB.x; t[5] += cB4.y * pB.y;
          t[6] += cB4.z * pB.z; t[7] += cB4.w * pB.w;
        }
        float tt = ((t[0]+t[1]) + (t[2]+t[3])) + ((t[4]+t[5]) + (t[6]+t[7]));
        float d = (sx + sc[k]) - 2.0f * tt;
        unsigned int db = __float_as_uint(d);
        unsigned int en = db ^ ((unsigned int)((int)db >> 31) | 0x80000000u);
        unsigned long long pk = ((unsigned long long)en << 32) | (unsigned int)k;
        if (pk < bestpack) bestpack = pk;
      }
      asm volatile("s_waitcnt lgkmcnt(0)" ::: "memory");
      if (pend == -2) { pend = -1; break; }
    }
  }
#pragma unroll
  for (int off = 32; off >= 1; off >>= 1) {
    unsigned long long o = __shfl_xor(bestpack, off, 64);
    if (o < bestpack) bestpack = o;
  }
  int bidx = (int)(unsigned int)(bestpack & 0xFFFFFFFFull);

  float qv = cb[(size_t)bidx * EDIM + lane];
  float diff = qv - xx;                              // fl(x_q - x)
  out_xq[(size_t)token * EDIM + lane] = xx + diff;   // fl(x + fl(x_q - x))
  if (lane == 0) out_idx[token] = (float)bidx;

  float l = diff * diff;
#pragma unroll
  for (int off = 32; off >= 1; off >>= 1) l += __shfl_down(l, off, 64);
  if (lane == 0) sdata[wv] = l;
  __syncthreads();
  if (tid == 0) partial[blockIdx.x] = sdata[0] + sdata[1];
}

// ---------------- final loss reduction ----------------------------------------------
__global__ __launch_bounds__(256) void vq_loss(const float* __restrict__ partial,
                                               float* __restrict__ out_loss) {
  int tid = threadIdx.x;
  float s = 0.0f;
  for (int i = tid; i < NTOK / 2; i += 256) s += partial[i];
#pragma unroll
  for (int off = 32; off >= 1; off >>= 1) s += __shfl_down(s, off, 64);
  __shared__ float sdata[4];
  if ((tid & 63) == 0) sdata[tid >> 6] = s;
  __syncthreads();
  if (tid == 0) {
    float total = (sdata[0] + sdata[1]) + (sdata[2] + sdata[3]);
    float m = total * (1.0f / (float)NELEM);
    out_loss[0] = m + 0.25f * m;
  }
}

// ---------------- launch -------------------------------------------------------------
extern "C" void kernel_launch(void* const* d_in, const int* in_sizes, int n_in,
                              void* d_out, int out_size, void* d_ws, size_t ws_size,
                              hipStream_t stream) {
  const float* x  = (const float*)d_in[0];
  const float* cb = (const float*)d_in[1];
  const int* p_start = (const int*)d_in[2];
  const int* p_end   = (const int*)d_in[3];

  float* ws = (float*)d_ws;
  float* sc      = ws;                                            // 8192 f
  float* partial = ws + N_E;                                      // 16384 f
  unsigned short* cbf    = (unsigned short*)(ws + N_E + NTOK/2);  // 8192*96 us (1.5MB)
  unsigned short* minima = cbf + (size_t)N_E * KEXT;              // 32768*256 us (16MB)

  float* out      = (float*)d_out;
  float* out_xq   = out;                 // 2097152
  float* out_loss = out + NELEM;         // 1
  float* out_idx  = out + NELEM + 1;     // 32768

  vq_sc<<<N_E / 256, 256, 0, stream>>>(cb, sc, cbf);
  dim3 g1(NTOK / TTOK, N_E / TCODE);
  vq_pass1<<<g1, 256, 0, stream>>>(x, cbf, minima, p_start, p_end);
  vq_rescue<<<NTOK / 2, 128, 0, stream>>>(x, cb, sc, minima, out_xq, out_idx,
                                          partial, p_start, p_end);
  vq_loss<<<1, 256, 0, stream>>>(partial, out_loss);
}

// Round 9
// 213.338 us; speedup vs baseline: 32.9407x; 1.0731x over previous
//
#include <hip/hip_runtime.h>
#include <math.h>

// VectorQuantizer: x (32768,64) f32, codebook (8192,64) f32, start/end/use_sk ints.
// Outputs concat: x_q_st (2097152 f32) | loss (1 f32) | indices (32768 as f32 values).
//
// R9: bf16-MFMA filter emits per-chunk CANDIDATE BITMASKS; rescue evaluates only
// masked codes (~2-3/token) with the BIT-EXACT R1 numpy-replica arithmetic.
//  vq_sc:   sc_k exact (pairwise-8 numpy replica, f32) + cb -> cbf_ext rows
//           [c0..c63, bf16(sc_k), 0*15] (K padded 64->80; sc folded via x-ext -0.5).
//  vq_pass1: 32x32x16 MFMA, block = 256 tokens x 2048 codes (16 iters of 128).
//           Per (token, 32-code chunk): f16 min g AND u32 mask of codes with
//           acc >= chunkmax_f32 - W/2  (== g_bf <= chunkmin + W).
//           LDS stride 88 ushorts (44 dwords == 4 mod 8): conflict-free b128 walk.
//  vq_rescue: wave/token, NO chunk staging. Butterfly min over f16 minima -> thr;
//           flagged lanes load their mask uint4; pop set bits; eval each candidate
//           from global cb with the BIT-EXACT R1 arithmetic (pairwise-8, separate
//           mul+add); lex-min (enc(d),k) == strict-< ascending-k first-occurrence.
// Exactness: ref argmin k* has g_bf(k*) <= chunkmin_f32 + 2*err_bf (1.6e-4 < W=3e-4)
// -> k* always in its chunk's mask; chunk always flagged (R6-validated f16 budget);
// lex-min over a superset containing the reference argmin == reference.
// DO NOT change the exact-path arithmetic: inter-code d gaps are ~1 ulp of d.

#define N_E    8192
#define EDIM   64
#define NTOK   32768
#define NELEM  (NTOK * EDIM)
#define CSZ    32                  // chunk size
#define NCHUNK (N_E / CSZ)         // 256 chunks
#define WINDOW 3e-4f
#define KEXT   80                  // padded K (64 data + sc-fold + zeros)
#define TTOK   256                 // pass-1 tokens per block
#define TCODE  2048                // pass-1 codes per block (16 iters of 128)
#define SROW   88                  // LDS row stride (ushorts; 44 dwords == 4 mod 8)

typedef __attribute__((ext_vector_type(8)))  short          short8;
typedef __attribute__((ext_vector_type(8)))  unsigned short ushort8v;
typedef __attribute__((ext_vector_type(4)))  unsigned short ushort4v;
typedef __attribute__((ext_vector_type(16))) float          f32x16;

__device__ __forceinline__ unsigned short f2bf(float f) {   // RTNE f32->bf16 bits
  unsigned int u = __float_as_uint(f);
  return (unsigned short)((u + 0x7FFFu + ((u >> 16) & 1u)) >> 16);
}
__device__ __forceinline__ unsigned short f2h(float f) {
  union { _Float16 h; unsigned short u; } cv; cv.h = (_Float16)f; return cv.u;
}
__device__ __forceinline__ float h2f(unsigned short b) {
  union { _Float16 h; unsigned short u; } cv; cv.u = b; return (float)cv.h;
}

// ---------------- sc (exact pairwise-8) + cb -> bf16 ext rows [c, sc, zeros] ---------
__global__ __launch_bounds__(256) void vq_sc(const float* __restrict__ cb,
                                             float* __restrict__ sc,
                                             unsigned short* __restrict__ cbf) {
#pragma clang fp contract(off)
  int r = blockIdx.x * 256 + threadIdx.x;
  const float4* c4 = (const float4*)(cb + (size_t)r * EDIM);
  float a[8];
#pragma unroll
  for (int j = 0; j < 8; ++j) a[j] = 0.0f;
#pragma unroll
  for (int i = 0; i < 8; ++i) {
    float4 pA = c4[2*i], pB = c4[2*i+1];
    a[0] += pA.x * pA.x; a[1] += pA.y * pA.y; a[2] += pA.z * pA.z; a[3] += pA.w * pA.w;
    a[4] += pB.x * pB.x; a[5] += pB.y * pB.y; a[6] += pB.z * pB.z; a[7] += pB.w * pB.w;
  }
  float sval = ((a[0]+a[1]) + (a[2]+a[3])) + ((a[4]+a[5]) + (a[6]+a[7]));
  sc[r] = sval;
  unsigned short* dst = cbf + (size_t)r * KEXT;
#pragma unroll
  for (int h = 0; h < 8; ++h) {
    float4 fA = c4[2*h], fB = c4[2*h+1];
    ushort8v o = {f2bf(fA.x), f2bf(fA.y), f2bf(fA.z), f2bf(fA.w),
                  f2bf(fB.x), f2bf(fB.y), f2bf(fB.z), f2bf(fB.w)};
    *(ushort8v*)&dst[h * 8] = o;
  }
  ushort8v t0 = {0,0,0,0,0,0,0,0};
  t0[0] = f2bf(sval);
  *(ushort8v*)&dst[64] = t0;
  ushort8v z = {0,0,0,0,0,0,0,0};
  *(ushort8v*)&dst[72] = z;
}

// ---------------- pass 1: 32x32x16 MFMA filter -> per-chunk min + candidate mask -----
// Frags: A[m=lane&31][k=8*(lane>>5)+j] (codes), B same (tokens),
// D: col=lane&31 (token), row=(reg&3)+8*(reg>>2)+4*(lane>>5) (code).
__global__ __launch_bounds__(256, 2) void vq_pass1(
    const float* __restrict__ x, const unsigned short* __restrict__ cbf,
    unsigned short* __restrict__ minima, unsigned int* __restrict__ maskb,
    const int* __restrict__ p_start, const int* __restrict__ p_end) {
  __shared__ unsigned short Xs[TTOK * SROW];   // 45056 B
  __shared__ unsigned short Cs[128 * SROW];    // 22528 B
  int tid = threadIdx.x;
  int tb = blockIdx.x;    // token split [0,128)
  int cbk = blockIdx.y;   // code split  [0,4)
  int s = *p_start, e = *p_end;

  // ---- stage x tile (fused f32 -> bf16-ext conversion) ----
  const float4* xg = (const float4*)(x + (size_t)tb * TTOK * EDIM);
#pragma unroll
  for (int p = 0; p < 16; ++p) {
    int idx = tid + p * 256;                   // [0,4096): row*16 + c4
    int row = idx >> 4, c4i = idx & 15;
    float4 f = xg[idx];
    ushort4v o = {f2bf(f.x), f2bf(f.y), f2bf(f.z), f2bf(f.w)};
    *(ushort4v*)&Xs[row * SROW + c4i * 4] = o;
  }
  {                                            // tail cols 64..79: [-0.5, zeros]
    ushort8v t0 = {0,0,0,0,0,0,0,0};
    t0[0] = f2bf(-0.5f);
    ushort8v z = {0,0,0,0,0,0,0,0};
    *(ushort8v*)&Xs[tid * SROW + 64] = t0;
    *(ushort8v*)&Xs[tid * SROW + 72] = z;
  }
  // ---- stage first code tile: 128 rows x 10 ushort8 = 1280 ----
  const ushort8v* cg0 = (const ushort8v*)(cbf + (size_t)cbk * TCODE * KEXT);
#pragma unroll
  for (int p = 0; p < 5; ++p) {
    int idx = tid + p * 256;
    int row = idx / 10, h = idx % 10;
    *(ushort8v*)&Cs[row * SROW + h * 8] = cg0[idx];
  }
  __syncthreads();

  int lane = tid & 63, wv = tid >> 6;
  int half = lane >> 5, ln = lane & 31;
  int tokbase = wv * 64;
  short8 bfr[2][5];
#pragma unroll
  for (int tg = 0; tg < 2; ++tg)
#pragma unroll
    for (int ks = 0; ks < 5; ++ks)
      bfr[tg][ks] = *(const short8*)&Xs[(tokbase + tg*32 + ln) * SROW + ks*16 + half*8];

  for (int nb = 0; nb < 16; ++nb) {
    ushort8v creg[5];
    if (nb < 15) {
      const ushort8v* cg =
          (const ushort8v*)(cbf + ((size_t)cbk * TCODE + (nb + 1) * 128) * KEXT);
#pragma unroll
      for (int p = 0; p < 5; ++p) creg[p] = cg[tid + p * 256];
    }
    f32x16 acc[2][4];
#pragma unroll
    for (int tg = 0; tg < 2; ++tg)
#pragma unroll
      for (int ct = 0; ct < 4; ++ct) acc[tg][ct] = (f32x16)0.0f;
#pragma unroll
    for (int ks = 0; ks < 5; ++ks)
#pragma unroll
      for (int ct = 0; ct < 4; ++ct) {
        short8 a = *(const short8*)&Cs[(ct*32 + ln) * SROW + ks*16 + half*8];
        acc[0][ct] = __builtin_amdgcn_mfma_f32_32x32x16_bf16(a, bfr[0][ks],
                                                             acc[0][ct], 0, 0, 0);
        acc[1][ct] = __builtin_amdgcn_mfma_f32_32x32x16_bf16(a, bfr[1][ks],
                                                             acc[1][ct], 0, 0, 0);
      }
    __syncthreads();                           // all Cs reads done
    if (nb < 15) {
#pragma unroll
      for (int p = 0; p < 5; ++p) {
        int idx = tid + p * 256;
        int row = idx / 10, h = idx % 10;
        *(ushort8v*)&Cs[row * SROW + h * 8] = creg[p];
      }
    }
    // epilogue (registers only; overlaps LDS writes): per-chunk max + candidate bits
    int cbase0 = cbk * TCODE + nb * 128;
    float vmv[2][4];
    unsigned mbits[2][4];
#pragma unroll
    for (int ct = 0; ct < 4; ++ct) {
      int c0 = cbase0 + ct * 32;
      bool full = (c0 >= s) && (c0 + 32 <= e);
#pragma unroll
      for (int tg = 0; tg < 2; ++tg) {
        float v = -INFINITY;
        if (full) {
#pragma unroll
          for (int r = 0; r < 16; ++r) v = fmaxf(v, acc[tg][ct][r]);
        } else {
#pragma unroll
          for (int r = 0; r < 16; ++r) {
            int code = c0 + (r & 3) + 8 * (r >> 2) + 4 * half;
            if (code >= s && code < e) v = fmaxf(v, acc[tg][ct][r]);
          }
        }
        v = fmaxf(v, __shfl_xor(v, 32, 64));   // chunk max in f32 acc space
        vmv[tg][ct] = v;
        float t = v - WINDOW * 0.5f;           // g_bf <= chunkmin + W  <=>  acc >= t
        unsigned b = 0;
#pragma unroll
        for (int r = 0; r < 16; ++r) {
          int pos = (r & 3) + 8 * (r >> 2) + 4 * half;
          if (acc[tg][ct][r] >= t) b |= (1u << pos);
        }
        b |= __shfl_xor(b, 32, 64);            // merge the two row-half groups
        mbits[tg][ct] = b;
      }
    }
    int token = tb * TTOK + tokbase + lane;    // lane's own token (tg = half)
    uint2 pk;
    pk.x = (unsigned int)f2h(-2.0f * vmv[half][0])
         | ((unsigned int)f2h(-2.0f * vmv[half][1]) << 16);
    pk.y = (unsigned int)f2h(-2.0f * vmv[half][2])
         | ((unsigned int)f2h(-2.0f * vmv[half][3]) << 16);
    *(uint2*)(minima + (size_t)token * NCHUNK + (cbase0 >> 5)) = pk;
    uint4 mq;
    mq.x = mbits[half][0]; mq.y = mbits[half][1];
    mq.z = mbits[half][2]; mq.w = mbits[half][3];
    *(uint4*)(maskb + (size_t)token * NCHUNK + (cbase0 >> 5)) = mq;
    __syncthreads();                           // Cs writes visible before next compute
  }
}

// ---------------- pass 2: mask-driven exact rescue + epilogue ------------------------
// Wave per token. Candidates (~2-3/token) evaluated straight from global cb with the
// BIT-EXACT R1 numpy-replica arithmetic. No chunk staging.
__global__ __launch_bounds__(256) void vq_rescue(
    const float* __restrict__ x, const float* __restrict__ cb,
    const float* __restrict__ sc, const unsigned short* __restrict__ minima,
    const unsigned int* __restrict__ maskb,
    float* __restrict__ out_xq, float* __restrict__ out_idx,
    float* __restrict__ partial,
    const int* __restrict__ p_start, const int* __restrict__ p_end) {
#pragma clang fp contract(off)
  __shared__ float xs[4][64];
  __shared__ float sdata[4];
  int tid  = threadIdx.x;
  int wv   = tid >> 6;
  int lane = tid & 63;
  int token = blockIdx.x * 4 + wv;

  float xx = x[(size_t)token * EDIM + lane];
  xs[wv][lane] = xx;
  __syncthreads();
  const float4* xl4 = (const float4*)xs[wv];

  // sx = np.sum(x*x) pairwise-8 replica
  float a[8];
#pragma unroll
  for (int j = 0; j < 8; ++j) a[j] = 0.0f;
#pragma unroll
  for (int i = 0; i < 8; ++i) {
    float4 pA = xl4[2*i], pB = xl4[2*i+1];
    a[0] += pA.x * pA.x; a[1] += pA.y * pA.y; a[2] += pA.z * pA.z; a[3] += pA.w * pA.w;
    a[4] += pB.x * pB.x; a[5] += pB.y * pB.y; a[6] += pB.z * pB.z; a[7] += pB.w * pB.w;
  }
  float sx = ((a[0]+a[1]) + (a[2]+a[3])) + ((a[4]+a[5]) + (a[6]+a[7]));

  // minima row: lane covers chunks 4*lane .. 4*lane+3 (coalesced uint2)
  uint2 u2 = *(const uint2*)(minima + (size_t)token * NCHUNK + lane * 4);
  float mv[4] = {h2f((unsigned short)(u2.x & 0xFFFFu)),
                 h2f((unsigned short)(u2.x >> 16)),
                 h2f((unsigned short)(u2.y & 0xFFFFu)),
                 h2f((unsigned short)(u2.y >> 16))};
  float m = fminf(fminf(mv[0], mv[1]), fminf(mv[2], mv[3]));
#pragma unroll
  for (int off = 32; off >= 1; off >>= 1) m = fminf(m, __shfl_xor(m, off, 64));
  float thr = m + WINDOW;

  int s = *p_start, e = *p_end;
  unsigned long long bestpack = ~0ull;

  bool anyf = (mv[0] <= thr) | (mv[1] <= thr) | (mv[2] <= thr) | (mv[3] <= thr);
  if (anyf) {
    uint4 mq = *(const uint4*)(maskb + (size_t)token * NCHUNK + lane * 4);
    unsigned mks[4] = {mq.x, mq.y, mq.z, mq.w};
#pragma unroll 1
    for (int cc = 0; cc < 4; ++cc) {
      if (!(mv[cc] <= thr)) continue;
      unsigned msk = mks[cc];
      while (msk) {
        int j = __ffs(msk) - 1;
        msk &= msk - 1;
        int k = (lane * 4 + cc) * CSZ + j;
        if (k >= s && k < e) {
          const float4* c4 = (const float4*)(cb + (size_t)k * EDIM);
          float t[8];
#pragma unroll
          for (int jj = 0; jj < 8; ++jj) t[jj] = 0.0f;
#pragma unroll
          for (int i = 0; i < 8; ++i) {        // elements 8i..8i+7, i ascending
            float4 cA4 = c4[2*i], cB4 = c4[2*i+1];
            float4 pA = xl4[2*i], pB = xl4[2*i+1];
            t[0] += cA4.x * pA.x; t[1] += cA4.y * pA.y;
            t[2] += cA4.z * pA.z; t[3] += cA4.w * pA.w;
            t[4] += cB4.x * pB.x; t[5] += cB4.y * pB.y;
            t[6] += cB4.z * pB.z; t[7] += cB4.w * pB.w;
          }
          float tt = ((t[0]+t[1]) + (t[2]+t[3])) + ((t[4]+t[5]) + (t[6]+t[7]));
          float d = (sx + sc[k]) - 2.0f * tt;
          unsigned int db = __float_as_uint(d);
          unsigned int en = db ^ ((unsigned int)((int)db >> 31) | 0x80000000u);
          unsigned long long pk = ((unsigned long long)en << 32) | (unsigned int)k;
          if (pk < bestpack) bestpack = pk;
        }
      }
    }
  }
  // lex-min reduce: (d asc, k asc) == numpy first-occurrence argmin
#pragma unroll
  for (int off = 32; off >= 1; off >>= 1) {
    unsigned long long o = __shfl_xor(bestpack, off, 64);
    if (o < bestpack) bestpack = o;
  }
  int bidx = (int)(unsigned int)(bestpack & 0xFFFFFFFFull);

  float qv = cb[(size_t)bidx * EDIM + lane];
  float diff = qv - xx;                              // fl(x_q - x)
  out_xq[(size_t)token * EDIM + lane] = xx + diff;   // fl(x + fl(x_q - x))
  if (lane == 0) out_idx[token] = (float)bidx;

  float l = diff * diff;
#pragma unroll
  for (int off = 32; off >= 1; off >>= 1) l += __shfl_down(l, off, 64);
  if (lane == 0) sdata[wv] = l;
  __syncthreads();
  if (tid == 0)
    partial[blockIdx.x] = (sdata[0] + sdata[1]) + (sdata[2] + sdata[3]);
}

// ---------------- final loss reduction ----------------------------------------------
__global__ __launch_bounds__(256) void vq_loss(const float* __restrict__ partial,
                                               float* __restrict__ out_loss) {
  int tid = threadIdx.x;
  float s = 0.0f;
  for (int i = tid; i < NTOK / 4; i += 256) s += partial[i];
#pragma unroll
  for (int off = 32; off >= 1; off >>= 1) s += __shfl_down(s, off, 64);
  __shared__ float sdata[4];
  if ((tid & 63) == 0) sdata[tid >> 6] = s;
  __syncthreads();
  if (tid == 0) {
    float total = (sdata[0] + sdata[1]) + (sdata[2] + sdata[3]);
    float m = total * (1.0f / (float)NELEM);
    out_loss[0] = m + 0.25f * m;
  }
}

// ---------------- launch -------------------------------------------------------------
extern "C" void kernel_launch(void* const* d_in, const int* in_sizes, int n_in,
                              void* d_out, int out_size, void* d_ws, size_t ws_size,
                              hipStream_t stream) {
  const float* x  = (const float*)d_in[0];
  const float* cb = (const float*)d_in[1];
  const int* p_start = (const int*)d_in[2];
  const int* p_end   = (const int*)d_in[3];

  float* ws = (float*)d_ws;
  float* sc      = ws;                                            // 8192 f
  float* partial = ws + N_E;                                      // 8192 f
  unsigned short* cbf    = (unsigned short*)(ws + 2 * N_E);       // 8192*80 us (1.3MB)
  unsigned short* minima = cbf + (size_t)N_E * KEXT;              // 32768*256 us (16MB)
  unsigned int*   maskb  = (unsigned int*)(minima + (size_t)NTOK * NCHUNK); // 32MB

  float* out      = (float*)d_out;
  float* out_xq   = out;                 // 2097152
  float* out_loss = out + NELEM;         // 1
  float* out_idx  = out + NELEM + 1;     // 32768

  vq_sc<<<N_E / 256, 256, 0, stream>>>(cb, sc, cbf);
  dim3 g1(NTOK / TTOK, N_E / TCODE);
  vq_pass1<<<g1, 256, 0, stream>>>(x, cbf, minima, maskb, p_start, p_end);
  vq_rescue<<<NTOK / 4, 256, 0, stream>>>(x, cb, sc, minima, maskb, out_xq, out_idx,
                                          partial, p_start, p_end);
  vq_loss<<<1, 256, 0, stream>>>(partial, out_loss);
}